// Round 1
// baseline (1460.323 us; speedup 1.0000x reference)
//
#include <hip/hip_runtime.h>
#include <stdint.h>

#define N_ROWS 65536
#define K_CODES 8192
#define D_DIM 512
#define EPS_NORM 1e-12f
#define NB 64            // number of 128-wide column blocks
#define MARGIN 2.5e-3f   // > 2x hard bound on fp16 dot error (2*1.01e-3)
#define CAP 16           // max per-row candidate codes on the light path

typedef _Float16 f16x8 __attribute__((ext_vector_type(8)));
typedef _Float16 f16x4 __attribute__((ext_vector_type(4)));
typedef float f32x4 __attribute__((ext_vector_type(4)));
typedef unsigned long long u64;

__device__ __forceinline__ unsigned orderf(float f) {
  unsigned u = __float_as_uint(f);
  return (u & 0x80000000u) ? ~u : (u | 0x80000000u);
}
__device__ __forceinline__ float unorderf(unsigned ub) {
  unsigned u = (ub & 0x80000000u) ? (ub & 0x7FFFFFFFu) : ~ub;
  return __uint_as_float(u);
}
__device__ __forceinline__ unsigned umin32(unsigned a, unsigned b) { return a < b ? a : b; }
__device__ __forceinline__ u64 umin64(u64 a, u64 b) { return a < b ? a : b; }
__device__ __forceinline__ u64 shfl_xor_u64(u64 v, int m) {
  unsigned lo = (unsigned)__shfl_xor((int)(unsigned)(v & 0xFFFFFFFFull), m, 64);
  unsigned hi = (unsigned)__shfl_xor((int)(unsigned)(v >> 32), m, 64);
  return ((u64)hi << 32) | (u64)lo;
}
__device__ __forceinline__ void async_copy16(void* lds, const void* g) {
  __builtin_amdgcn_global_load_lds(
      (const __attribute__((address_space(1))) void*)g,
      (__attribute__((address_space(3))) void*)lds, 16, 0, 0);
}

// ---------------------------------------------------------------------------
// prep: L2-normalize rows (F.normalize semantics), emit fp16 copy for MFMA.
// ---------------------------------------------------------------------------
__global__ __launch_bounds__(64) void prep_z_kernel(
    const float* __restrict__ z, _Float16* __restrict__ znh,
    float* __restrict__ znorm, float* __restrict__ znorm2) {
  const int row = blockIdx.x;
  const int lane = threadIdx.x;
  const float4* xr = (const float4*)(z + (size_t)row * D_DIM);
  float4 v0 = xr[lane];
  float4 v1 = xr[lane + 64];
  float ss = v0.x * v0.x + v0.y * v0.y + v0.z * v0.z + v0.w * v0.w
           + v1.x * v1.x + v1.y * v1.y + v1.z * v1.z + v1.w * v1.w;
#pragma unroll
  for (int s = 32; s > 0; s >>= 1) ss += __shfl_xor(ss, s, 64);
  const float m = fmaxf(sqrtf(ss), EPS_NORM);
  float4 o0, o1;
  o0.x = v0.x / m; o0.y = v0.y / m; o0.z = v0.z / m; o0.w = v0.w / m;
  o1.x = v1.x / m; o1.y = v1.y / m; o1.z = v1.z / m; o1.w = v1.w / m;
  float s2 = o0.x * o0.x + o0.y * o0.y + o0.z * o0.z + o0.w * o0.w
           + o1.x * o1.x + o1.y * o1.y + o1.z * o1.z + o1.w * o1.w;
#pragma unroll
  for (int s = 32; s > 0; s >>= 1) s2 += __shfl_xor(s2, s, 64);
  f16x4 h0, h1;
  h0[0] = (_Float16)o0.x; h0[1] = (_Float16)o0.y; h0[2] = (_Float16)o0.z; h0[3] = (_Float16)o0.w;
  h1[0] = (_Float16)o1.x; h1[1] = (_Float16)o1.y; h1[2] = (_Float16)o1.z; h1[3] = (_Float16)o1.w;
  *(f16x4*)(znh + (size_t)row * D_DIM + lane * 4) = h0;
  *(f16x4*)(znh + (size_t)row * D_DIM + 256 + lane * 4) = h1;
  if (lane == 0) { znorm[row] = m; znorm2[row] = s2; }
}

__global__ __launch_bounds__(64) void prep_cb_kernel(
    const float* __restrict__ emb, float* __restrict__ cb32,
    _Float16* __restrict__ cbh, float* __restrict__ cnorm2) {
  const int row = blockIdx.x;
  const int lane = threadIdx.x;
  const float4* xr = (const float4*)(emb + (size_t)row * D_DIM);
  float4 v0 = xr[lane];
  float4 v1 = xr[lane + 64];
  float ss = v0.x * v0.x + v0.y * v0.y + v0.z * v0.z + v0.w * v0.w
           + v1.x * v1.x + v1.y * v1.y + v1.z * v1.z + v1.w * v1.w;
#pragma unroll
  for (int s = 32; s > 0; s >>= 1) ss += __shfl_xor(ss, s, 64);
  const float m = fmaxf(sqrtf(ss), EPS_NORM);
  float4 o0, o1;
  o0.x = v0.x / m; o0.y = v0.y / m; o0.z = v0.z / m; o0.w = v0.w / m;
  o1.x = v1.x / m; o1.y = v1.y / m; o1.z = v1.z / m; o1.w = v1.w / m;
  float s2 = o0.x * o0.x + o0.y * o0.y + o0.z * o0.z + o0.w * o0.w
           + o1.x * o1.x + o1.y * o1.y + o1.z * o1.z + o1.w * o1.w;
#pragma unroll
  for (int s = 32; s > 0; s >>= 1) s2 += __shfl_xor(s2, s, 64);
  float4* co = (float4*)(cb32 + (size_t)row * D_DIM);
  co[lane] = o0;
  co[lane + 64] = o1;
  f16x4 h0, h1;
  h0[0] = (_Float16)o0.x; h0[1] = (_Float16)o0.y; h0[2] = (_Float16)o0.z; h0[3] = (_Float16)o0.w;
  h1[0] = (_Float16)o1.x; h1[1] = (_Float16)o1.y; h1[2] = (_Float16)o1.z; h1[3] = (_Float16)o1.w;
  *(f16x4*)(cbh + (size_t)row * D_DIM + lane * 4) = h0;
  *(f16x4*)(cbh + (size_t)row * D_DIM + 256 + lane * 4) = h1;
  if (lane == 0) cnorm2[row] = s2;
}

__global__ void zero_count_kernel(unsigned* __restrict__ counters) {
  if (threadIdx.x < 2) counters[threadIdx.x] = 0;
}

// ---------------------------------------------------------------------------
// Screening GEMM v3: 256x256 tile, BK=64, 8 waves (2M x 4N), 8-phase
// counted-vmcnt pipeline (T3+T4), LDS chunk-XOR swizzle via pre-swizzled
// global_load_lds sources (T2), setprio around MFMA clusters (T5).
// Each wave owns a 128x64 C strip; acc[8][4] f32x4. D=512 -> 8 K-tiles,
// 2 tiles per 8-phase iteration, double-buffered 128 KiB LDS.
// Epilogue: per-row top-1 key / top-2 value per 128-col group (NB=64 layout
// identical to v2, so certify/light/heavy are unchanged).
// ---------------------------------------------------------------------------

#define LDSA0 0
#define LDSA1 16384
#define LDSB0 32768
#define LDSB1 49152

#define STG1(ldsOff, srcp, half, i, kt)                                       \
  async_copy16(lds + (ldsOff) + ((half) * 128 + (i) * 64 + wv * 8) * 64,      \
               (srcp) + ((half) * 128 + (i) * 64) * (size_t)D_DIM + (kt) * 64)
#define STGH(ldsOff, srcp, half, kt)                                          \
  do { STG1(ldsOff, srcp, half, 0, kt); STG1(ldsOff, srcp, half, 1, kt); } while (0)

#define LDA(boff, mh)                                                         \
  do {                                                                        \
    _Pragma("unroll") for (int mf_ = 0; mf_ < 4; ++mf_) {                     \
      const _Float16* p_ = lds + (boff) + aRd + ((mh) * 64 + mf_ * 16) * 64;  \
      aF[mf_][0] = *(const f16x8*)(p_ + ck0);                                 \
      aF[mf_][1] = *(const f16x8*)(p_ + ck1);                                 \
    }                                                                         \
  } while (0)

#define LDB(dst, boff, nh)                                                    \
  do {                                                                        \
    _Pragma("unroll") for (int nf_ = 0; nf_ < 2; ++nf_) {                     \
      const _Float16* p_ = lds + (boff) + bRd + ((nh) * 32 + nf_ * 16) * 64;  \
      dst[nf_][0] = *(const f16x8*)(p_ + ck0);                                \
      dst[nf_][1] = *(const f16x8*)(p_ + ck1);                                \
    }                                                                         \
  } while (0)

#define MM(mh, nh, BF)                                                        \
  do {                                                                        \
    _Pragma("unroll") for (int mf_ = 0; mf_ < 4; ++mf_) {                     \
      _Pragma("unroll") for (int nf_ = 0; nf_ < 2; ++nf_) {                   \
        acc[(mh) * 4 + mf_][(nh) * 2 + nf_] =                                 \
            __builtin_amdgcn_mfma_f32_16x16x32_f16(                           \
                aF[mf_][0], BF[nf_][0],                                       \
                acc[(mh) * 4 + mf_][(nh) * 2 + nf_], 0, 0, 0);                \
        acc[(mh) * 4 + mf_][(nh) * 2 + nf_] =                                 \
            __builtin_amdgcn_mfma_f32_16x16x32_f16(                           \
                aF[mf_][1], BF[nf_][1],                                       \
                acc[(mh) * 4 + mf_][(nh) * 2 + nf_], 0, 0, 0);                \
      }                                                                       \
    }                                                                         \
  } while (0)

#define BARF                                                                  \
  do { asm volatile("" ::: "memory"); __builtin_amdgcn_s_barrier();           \
       asm volatile("" ::: "memory"); } while (0)
#define LGKM0 asm volatile("s_waitcnt lgkmcnt(0)" ::: "memory")
#define VM6 asm volatile("s_waitcnt vmcnt(6)" ::: "memory")
#define VM0 asm volatile("s_waitcnt vmcnt(0)" ::: "memory")
#define PRIO1 __builtin_amdgcn_s_setprio(1)
#define PRIO0 __builtin_amdgcn_s_setprio(0)

__global__ __launch_bounds__(512, 2) void screen_gemm_kernel(
    const _Float16* __restrict__ znh, const _Float16* __restrict__ cbh,
    u64* __restrict__ K1, unsigned* __restrict__ K2) {
  __shared__ __align__(16) _Float16 lds[65536];  // 128 KiB
  const int tid = (int)threadIdx.x;
  const int lane = tid & 63;
  const int wv = tid >> 6;     // wave 0..7
  const int wm = wv >> 2;      // 0..1: 128-row strip
  const int wn = wv & 3;       // 0..3: 64-col strip
  const int q = lane >> 4;     // 0..3
  const int c15 = lane & 15;
  const int m0 = (int)blockIdx.y * 256;
  const int n0 = (int)blockIdx.x * 256;

  // Staging sources, chunk-XOR pre-swizzled: linear LDS fill then yields
  // slot (row, c) holding global 16B-chunk c ^ (row&7)  (T2 via m173).
  const int srow = tid >> 3;                      // 0..63 within one issue
  const int schunk = (tid & 7) ^ (srow & 7);
  const _Float16* aS = znh + (size_t)(m0 + srow) * D_DIM + schunk * 8;
  const _Float16* bS = cbh + (size_t)(n0 + srow) * D_DIM + schunk * 8;

  // ds_read bases (element units) + swizzled chunk offsets for kf=0,1
  const int aRd = (wm * 128 + c15) * 64;
  const int bRd = (wn * 64 + c15) * 64;
  const int ck0 = ((q) ^ (c15 & 7)) * 8;
  const int ck1 = ((4 + q) ^ (c15 & 7)) * 8;

  f32x4 acc[8][4];
  const f32x4 z4 = {0.0f, 0.0f, 0.0f, 0.0f};
#pragma unroll
  for (int i = 0; i < 8; i++)
#pragma unroll
    for (int j = 0; j < 4; j++) acc[i][j] = z4;
  f16x8 aF[4][2], bF0[2][2], bF1[2][2];

  // -------- prologue: tile0 -> buf0 (8 loads), tile1 B + A.h0 -> buf1 (6)
  STGH(LDSA0, aS, 0, 0); STGH(LDSA0, aS, 1, 0);
  STGH(LDSB0, bS, 0, 0); STGH(LDSB0, bS, 1, 0);
  STGH(LDSB1, bS, 0, 1); STGH(LDSB1, bS, 1, 1);
  STGH(LDSA1, aS, 0, 1);
  VM6;   // tile0's 8 loads retired; 6 of tile1 in flight
  BARF;

  // -------- main loop: iterations 0..2 compute tiles (2it, 2it+1),
  //          stage tiles (2it+2 -> buf0, 2it+3 -> buf1)
  for (int it = 0; it < 3; ++it) {
    const int kE = 2 * it + 2, kO = 2 * it + 3;
    // ph1: Q(0,0) buf0; stage A.h1 of current odd tile -> buf1
    LDA(LDSA0, 0); LDB(bF0, LDSB0, 0);
    STGH(LDSA1, aS, 1, kO - 2);
    BARF; LGKM0; PRIO1; MM(0, 0, bF0); PRIO0; BARF;
    // ph2: Q(0,1) buf0
    LDB(bF1, LDSB0, 1);
    BARF; LGKM0; PRIO1; MM(0, 1, bF1); PRIO0; BARF;
    // ph3: Q(1,1) buf0; stage B.h0(kE) (buf0.B fully read after ph2)
    LDA(LDSA0, 1);
    STGH(LDSB0, bS, 0, kE);
    BARF; LGKM0; PRIO1; MM(1, 1, bF1); PRIO0; BARF;
    // ph4: Q(1,0) buf0; stage B.h1(kE)+A.h0(kE); vmcnt(6) -> tile(2it+1) landed
    STGH(LDSB0, bS, 1, kE); STGH(LDSA0, aS, 0, kE);
    BARF; PRIO1; MM(1, 0, bF0); PRIO0; VM6; BARF;
    // ph5: Q(0,0) buf1; stage A.h1(kE)
    LDA(LDSA1, 0); LDB(bF0, LDSB1, 0);
    STGH(LDSA0, aS, 1, kE);
    BARF; LGKM0; PRIO1; MM(0, 0, bF0); PRIO0; BARF;
    // ph6: Q(0,1) buf1
    LDB(bF1, LDSB1, 1);
    BARF; LGKM0; PRIO1; MM(0, 1, bF1); PRIO0; BARF;
    // ph7: Q(1,1) buf1; stage B.h0(kO)
    LDA(LDSA1, 1);
    STGH(LDSB1, bS, 0, kO);
    BARF; LGKM0; PRIO1; MM(1, 1, bF1); PRIO0; BARF;
    // ph8: Q(1,0) buf1; stage B.h1(kO)+A.h0(kO); vmcnt(6) -> tile kE landed
    STGH(LDSB1, bS, 1, kO); STGH(LDSA1, aS, 0, kO);
    BARF; PRIO1; MM(1, 0, bF0); PRIO0; VM6; BARF;
  }

  // -------- peeled last iteration (tiles 6,7) — only A.h1(7) left to stage
  LDA(LDSA0, 0); LDB(bF0, LDSB0, 0);
  STGH(LDSA1, aS, 1, 7);
  BARF; LGKM0; PRIO1; MM(0, 0, bF0); PRIO0; BARF;
  LDB(bF1, LDSB0, 1);
  BARF; LGKM0; PRIO1; MM(0, 1, bF1); PRIO0; BARF;
  LDA(LDSA0, 1);
  BARF; LGKM0; PRIO1; MM(1, 1, bF1); PRIO0; BARF;
  BARF; PRIO1; MM(1, 0, bF0); PRIO0; VM0; BARF;   // drain A.h1(7)
  LDA(LDSA1, 0); LDB(bF0, LDSB1, 0);
  BARF; LGKM0; PRIO1; MM(0, 0, bF0); PRIO0; BARF;
  LDB(bF1, LDSB1, 1);
  BARF; LGKM0; PRIO1; MM(0, 1, bF1); PRIO0; BARF;
  LDA(LDSA1, 1);
  BARF; LGKM0; PRIO1; MM(1, 1, bF1); PRIO0; BARF;
  PRIO1; MM(1, 0, bF0); PRIO0;

  // -------- epilogue: per-row top1 key / top2 val per 128-col group.
  // Wave-local reduce over (nf, c15), then pairwise merge of the two waves
  // sharing (row-strip, group) via LDS (A-buf0 region, all reads done).
  u64* kbuf = (u64*)lds;                       // [256 rows][2 grp][2 half]
  unsigned* vbuf = (unsigned*)(lds + 4096);    // bytes 8192..12287
#pragma unroll
  for (int mf = 0; mf < 8; ++mf) {
#pragma unroll
    for (int r = 0; r < 4; ++r) {
      u64 key1 = ~0ull;
      unsigned b2 = 0xFFFFFFFFu;
#pragma unroll
      for (int nf = 0; nf < 4; ++nf) {
        unsigned ub = orderf(-acc[mf][nf][r]);
        unsigned col = (unsigned)(n0 + wn * 64 + nf * 16 + c15);
        u64 k = ((u64)ub << 32) | (u64)col;
        unsigned v1 = (unsigned)(key1 >> 32);
        if (k < key1) { b2 = umin32(b2, v1); key1 = k; }
        else          { b2 = umin32(b2, ub); }
      }
#pragma unroll
      for (int s = 1; s <= 8; s <<= 1) {
        u64 ok = shfl_xor_u64(key1, s);
        unsigned ob2 = (unsigned)__shfl_xor((int)b2, s, 64);
        unsigned ov = (unsigned)(ok >> 32);
        unsigned v1k = (unsigned)(key1 >> 32);
        unsigned lose = (ok < key1) ? v1k : ov;
        b2 = umin32(umin32(b2, ob2), lose);
        key1 = umin64(key1, ok);
      }
      if (c15 == 0) {
        const int rowB = wm * 128 + mf * 16 + q * 4 + r;
        const int slot = (rowB * 2 + (wn >> 1)) * 2 + (wn & 1);
        kbuf[slot] = key1;
        vbuf[slot] = b2;
      }
    }
  }
  __syncthreads();
  {
    const int rowB = tid >> 1, g = tid & 1;
    const int base = (rowB * 2 + g) * 2;
    u64 k0 = kbuf[base], k1 = kbuf[base + 1];
    unsigned v0 = vbuf[base], v1 = vbuf[base + 1];
    u64 kk = umin64(k0, k1);
    unsigned lose = (k0 < k1) ? (unsigned)(k1 >> 32) : (unsigned)(k0 >> 32);
    unsigned t2 = umin32(umin32(v0, v1), lose);
    const size_t o = (size_t)(m0 + rowB) * NB + (size_t)blockIdx.x * 2 + g;
    K1[o] = kk;
    K2[o] = t2;
  }
}

// ---------------------------------------------------------------------------
// Certify v2: one wave per row, lane = block.
//  thr = approx_top1 + MARGIN.
//  - any block with top2 <= thr, or >CAP candidates  -> heavy list (rare)
//  - exactly 1 candidate code                        -> certified, done
//  - else                                            -> light list + compact
//                                                       candidate code array
// ---------------------------------------------------------------------------
__global__ __launch_bounds__(256) void certify_kernel(
    const u64* __restrict__ K1, const unsigned* __restrict__ K2,
    unsigned* __restrict__ idx_final, unsigned* __restrict__ candList,
    unsigned* __restrict__ candCount, unsigned* __restrict__ lightList,
    unsigned* __restrict__ heavyList, unsigned* __restrict__ counters) {
  const int row = blockIdx.x * 4 + (int)(threadIdx.x >> 6);
  const int b = (int)(threadIdx.x & 63);
  u64 k = K1[(size_t)row * NB + b];
  unsigned t2 = K2[(size_t)row * NB + b];
  u64 kmin = k;
#pragma unroll
  for (int s = 1; s <= 32; s <<= 1) kmin = umin64(kmin, shfl_xor_u64(kmin, s));
  const float t1f = unorderf((unsigned)(kmin >> 32));
  const unsigned thr = orderf(t1f + MARGIN);
  const bool cand = ((unsigned)(k >> 32)) <= thr;
  const bool heavy = (t2 <= thr);
  u64 cmask = __ballot(cand);
  u64 hmask = __ballot(heavy);
  const int nc = __popcll(cmask);
  if (hmask != 0 || nc > CAP) {
    if (b == 0) {
      unsigned p = atomicAdd(counters + 1, 1u);
      heavyList[p] = (unsigned)row;
    }
  } else if (nc == 1) {
    if (b == 0) idx_final[row] = (unsigned)(kmin & 0xFFFFFFFFull);
  } else {
    if (cand) {
      int pos = __popcll(cmask & ((b == 0) ? 0ull : (~0ull >> (64 - b))));
      candList[(size_t)row * CAP + pos] = (unsigned)(k & 0xFFFFFFFFull);
    }
    if (b == 0) {
      candCount[row] = (unsigned)nc;
      unsigned p = atomicAdd(counters + 0, 1u);
      lightList[p] = (unsigned)row;
    }
  }
}

// ---------------------------------------------------------------------------
// Light rescore: one wave per flagged row; exact fp32 dist for each candidate
// code (coalesced 2KB row reads), argmin with lowest-index tie-break.
// ---------------------------------------------------------------------------
__global__ __launch_bounds__(64) void rescore_light_kernel(
    const float* __restrict__ z, const float* __restrict__ cb32,
    const float* __restrict__ znorm, const float* __restrict__ znorm2,
    const float* __restrict__ cnorm2, const unsigned* __restrict__ candList,
    const unsigned* __restrict__ candCount,
    const unsigned* __restrict__ lightList,
    const unsigned* __restrict__ counters, unsigned* __restrict__ idx_final) {
  const int lane = (int)threadIdx.x;
  const unsigned n = counters[0];
  for (unsigned i = blockIdx.x; i < n; i += gridDim.x) {
    const int row = (int)lightList[i];
    const float m = znorm[row];
    const float zn2 = znorm2[row];
    const float4* zr = (const float4*)(z + (size_t)row * D_DIM);
    float4 v0 = zr[lane], v1 = zr[lane + 64];
    float4 o0, o1;
    o0.x = v0.x / m; o0.y = v0.y / m; o0.z = v0.z / m; o0.w = v0.w / m;
    o1.x = v1.x / m; o1.y = v1.y / m; o1.z = v1.z / m; o1.w = v1.w / m;
    const unsigned nc = candCount[row];
    u64 best = ~0ull;
    for (unsigned j = 0; j < nc; j++) {
      const unsigned c = candList[(size_t)row * CAP + j];
      const float4* qr = (const float4*)(cb32 + (size_t)c * D_DIM);
      float4 q0 = qr[lane], q1 = qr[lane + 64];
      float p = o0.x * q0.x + o0.y * q0.y + o0.z * q0.z + o0.w * q0.w
              + o1.x * q1.x + o1.y * q1.y + o1.z * q1.z + o1.w * q1.w;
#pragma unroll
      for (int s = 32; s > 0; s >>= 1) p += __shfl_xor(p, s, 64);
      float dist = __fadd_rn(__fsub_rn(zn2, __fmul_rn(2.0f, p)), cnorm2[c]);
      u64 key = ((u64)orderf(dist) << 32) | (u64)c;
      best = umin64(best, key);
    }
    if (lane == 0) idx_final[row] = (unsigned)(best & 0xFFFFFFFFull);
  }
}

// ---------------------------------------------------------------------------
// Heavy rescore (rare rows): full fp32 scan of every block whose top-1 is
// within MARGIN (superset of all candidates). Round-2 semantics.
// ---------------------------------------------------------------------------
__global__ __launch_bounds__(64) void rescore_heavy_kernel(
    const float* __restrict__ z, const float* __restrict__ cb32,
    const float* __restrict__ znorm, const float* __restrict__ znorm2,
    const float* __restrict__ cnorm2, const u64* __restrict__ K1,
    const unsigned* __restrict__ heavyList,
    const unsigned* __restrict__ counters, unsigned* __restrict__ idx_final) {
  __shared__ float znl[D_DIM];
  const int lane = (int)threadIdx.x;
  const unsigned n = counters[1];
  for (unsigned i = blockIdx.x; i < n; i += gridDim.x) {
    const int row = (int)heavyList[i];
    const float m = znorm[row];
    const float4* zr = (const float4*)(z + (size_t)row * D_DIM);
    float4 v0 = zr[lane], v1 = zr[lane + 64];
    __syncthreads();
    float4 o0, o1;
    o0.x = v0.x / m; o0.y = v0.y / m; o0.z = v0.z / m; o0.w = v0.w / m;
    o1.x = v1.x / m; o1.y = v1.y / m; o1.z = v1.z / m; o1.w = v1.w / m;
    *(float4*)&znl[lane * 4] = o0;
    *(float4*)&znl[256 + lane * 4] = o1;
    u64 k = K1[(size_t)row * NB + lane];
    u64 kmin = k;
#pragma unroll
    for (int s = 1; s <= 32; s <<= 1) kmin = umin64(kmin, shfl_xor_u64(kmin, s));
    const float t1 = unorderf((unsigned)(kmin >> 32));
    const bool cf = unorderf((unsigned)(k >> 32)) <= t1 + MARGIN;
    u64 mask = __ballot(cf);
    __syncthreads();
    const float zn2 = znorm2[row];
    u64 best = ~0ull;
    while (mask) {
      const int b = __builtin_ctzll(mask);
      mask &= mask - 1;
#pragma unroll
      for (int h = 0; h < 2; h++) {
        const int c = b * 128 + h * 64 + lane;
        const float4* cr = (const float4*)(cb32 + (size_t)c * D_DIM);
        float dot = 0.0f;
        for (int d = 0; d < 128; d++) {
          float4 bb = cr[d];
          float4 aa = *(const float4*)&znl[d * 4];
          dot = __fmaf_rn(aa.x, bb.x, dot);
          dot = __fmaf_rn(aa.y, bb.y, dot);
          dot = __fmaf_rn(aa.z, bb.z, dot);
          dot = __fmaf_rn(aa.w, bb.w, dot);
        }
        float dist = __fadd_rn(__fsub_rn(zn2, __fmul_rn(2.0f, dot)), cnorm2[c]);
        u64 key = ((u64)orderf(dist) << 32) | (u64)(unsigned)c;
        best = umin64(best, key);
      }
    }
#pragma unroll
    for (int s = 1; s <= 32; s <<= 1) best = umin64(best, shfl_xor_u64(best, s));
    if (lane == 0) idx_final[row] = (unsigned)(best & 0xFFFFFFFFull);
  }
}

// ---------------------------------------------------------------------------
// Finalize: gather code, project, write outputs. One wave per row.
// ---------------------------------------------------------------------------
__global__ __launch_bounds__(64) void finalize_kernel(
    const float* __restrict__ z, const float* __restrict__ cb32,
    const float* __restrict__ znorm, const unsigned* __restrict__ idx_final,
    float* __restrict__ out) {
  const int row = blockIdx.x;
  const int lane = (int)threadIdx.x;
  const float m = znorm[row];
  const unsigned idx = idx_final[row];
  const float4* zr = (const float4*)(z + (size_t)row * D_DIM);
  const float4* qr = (const float4*)(cb32 + (size_t)idx * D_DIM);
  float4 v0 = zr[lane], v1 = zr[lane + 64];
  float4 q0 = qr[lane], q1 = qr[lane + 64];
  float4 z0, z1;
  z0.x = v0.x / m; z0.y = v0.y / m; z0.z = v0.z / m; z0.w = v0.w / m;
  z1.x = v1.x / m; z1.y = v1.y / m; z1.z = v1.z / m; z1.w = v1.w / m;
  float p = z0.x * q0.x + z0.y * q0.y + z0.z * q0.z + z0.w * q0.w
          + z1.x * q1.x + z1.y * q1.y + z1.z * q1.z + z1.w * q1.w;
#pragma unroll
  for (int s = 32; s > 0; s >>= 1) p += __shfl_xor(p, s, 64);
  float4 o0, o1;
  o0.x = p * q0.x; o0.y = p * q0.y; o0.z = p * q0.z; o0.w = p * q0.w;
  o1.x = p * q1.x; o1.y = p * q1.y; o1.z = p * q1.z; o1.w = p * q1.w;
  float4* orow = (float4*)(out + (size_t)row * D_DIM);
  orow[lane] = o0;
  orow[lane + 64] = o1;
  if (lane == 0) out[(size_t)N_ROWS * D_DIM + row] = (float)idx;
}

// ---------------------------------------------------------------------------
extern "C" void kernel_launch(void* const* d_in, const int* in_sizes, int n_in,
                              void* d_out, int out_size, void* d_ws,
                              size_t ws_size, hipStream_t stream) {
  const float* z = (const float*)d_in[0];
  const float* emb = (const float*)d_in[1];
  float* out = (float*)d_out;

  // ws layout, ~142 MB total:
  u64* K1 = (u64*)d_ws;                                   // 32 MB
  unsigned* K2 = (unsigned*)(K1 + (size_t)N_ROWS * NB);   // 16 MB
  float* cb32 = (float*)(K2 + (size_t)N_ROWS * NB);       // 16 MB
  float* znorm = cb32 + (size_t)K_CODES * D_DIM;          // 256 KB
  float* znorm2 = znorm + N_ROWS;                         // 256 KB
  float* cnorm2 = znorm2 + N_ROWS;                        // 32 KB
  unsigned* idx_final = (unsigned*)(cnorm2 + K_CODES);    // 256 KB
  unsigned* lightList = idx_final + N_ROWS;               // 256 KB
  unsigned* heavyList = lightList + N_ROWS;               // 256 KB
  unsigned* candCount = heavyList + N_ROWS;               // 256 KB
  unsigned* counters = candCount + N_ROWS;                // 64*4 pad
  unsigned* candList = counters + 64;                     // 4 MB
  _Float16* znh = (_Float16*)(candList + (size_t)N_ROWS * CAP);  // 64 MB
  _Float16* cbh = znh + (size_t)N_ROWS * D_DIM;           // 8 MB

  prep_z_kernel<<<N_ROWS, 64, 0, stream>>>(z, znh, znorm, znorm2);
  prep_cb_kernel<<<K_CODES, 64, 0, stream>>>(emb, cb32, cbh, cnorm2);
  zero_count_kernel<<<1, 64, 0, stream>>>(counters);

  dim3 grid(K_CODES / 256, N_ROWS / 256);   // (32, 256)
  screen_gemm_kernel<<<grid, 512, 0, stream>>>(znh, cbh, K1, K2);

  certify_kernel<<<N_ROWS / 4, 256, 0, stream>>>(
      K1, K2, idx_final, candList, candCount, lightList, heavyList, counters);
  rescore_light_kernel<<<8192, 64, 0, stream>>>(
      z, cb32, znorm, znorm2, cnorm2, candList, candCount, lightList, counters,
      idx_final);
  rescore_heavy_kernel<<<512, 64, 0, stream>>>(
      z, cb32, znorm, znorm2, cnorm2, K1, heavyList, counters, idx_final);
  finalize_kernel<<<N_ROWS, 64, 0, stream>>>(z, cb32, znorm, idx_final, out);
}

// Round 2
// 1395.961 us; speedup vs baseline: 1.0461x; 1.0461x over previous
//
#include <hip/hip_runtime.h>
#include <stdint.h>

#define N_ROWS 65536
#define K_CODES 8192
#define D_DIM 512
#define EPS_NORM 1e-12f
#define NB 64            // number of 128-wide column blocks
#define MARGIN 2.5e-3f   // > 2x hard bound on fp16 dot error (2*1.01e-3)
#define CAP 16           // max per-row candidate codes on the light path

typedef _Float16 f16x8 __attribute__((ext_vector_type(8)));
typedef _Float16 f16x4 __attribute__((ext_vector_type(4)));
typedef float f32x4 __attribute__((ext_vector_type(4)));
typedef unsigned long long u64;

__device__ __forceinline__ unsigned orderf(float f) {
  unsigned u = __float_as_uint(f);
  return (u & 0x80000000u) ? ~u : (u | 0x80000000u);
}
__device__ __forceinline__ float unorderf(unsigned ub) {
  unsigned u = (ub & 0x80000000u) ? (ub & 0x7FFFFFFFu) : ~ub;
  return __uint_as_float(u);
}
__device__ __forceinline__ unsigned umin32(unsigned a, unsigned b) { return a < b ? a : b; }
__device__ __forceinline__ u64 umin64(u64 a, u64 b) { return a < b ? a : b; }
__device__ __forceinline__ u64 shfl_xor_u64(u64 v, int m) {
  unsigned lo = (unsigned)__shfl_xor((int)(unsigned)(v & 0xFFFFFFFFull), m, 64);
  unsigned hi = (unsigned)__shfl_xor((int)(unsigned)(v >> 32), m, 64);
  return ((u64)hi << 32) | (u64)lo;
}
__device__ __forceinline__ void async_copy16(void* lds, const void* g) {
  __builtin_amdgcn_global_load_lds(
      (const __attribute__((address_space(1))) void*)g,
      (__attribute__((address_space(3))) void*)lds, 16, 0, 0);
}

// ---------------------------------------------------------------------------
// prep: L2-normalize rows (F.normalize semantics), emit fp16 copy for MFMA.
// 4 rows per 256-thread block. prep_z uses rm-multiply (argmin-safe: all
// exact-path consumers re-divide raw z; znorm2 shift is row-constant).
// ---------------------------------------------------------------------------
__global__ __launch_bounds__(256) void prep_z_kernel(
    const float* __restrict__ z, _Float16* __restrict__ znh,
    float* __restrict__ znorm, float* __restrict__ znorm2) {
  const int row = blockIdx.x * 4 + ((int)threadIdx.x >> 6);
  const int lane = (int)threadIdx.x & 63;
  const float4* xr = (const float4*)(z + (size_t)row * D_DIM);
  float4 v0 = xr[lane];
  float4 v1 = xr[lane + 64];
  float ss = v0.x * v0.x + v0.y * v0.y + v0.z * v0.z + v0.w * v0.w
           + v1.x * v1.x + v1.y * v1.y + v1.z * v1.z + v1.w * v1.w;
#pragma unroll
  for (int s = 32; s > 0; s >>= 1) ss += __shfl_xor(ss, s, 64);
  const float m = fmaxf(sqrtf(ss), EPS_NORM);
  const float rm = 1.0f / m;
  float4 o0, o1;
  o0.x = v0.x * rm; o0.y = v0.y * rm; o0.z = v0.z * rm; o0.w = v0.w * rm;
  o1.x = v1.x * rm; o1.y = v1.y * rm; o1.z = v1.z * rm; o1.w = v1.w * rm;
  float s2 = o0.x * o0.x + o0.y * o0.y + o0.z * o0.z + o0.w * o0.w
           + o1.x * o1.x + o1.y * o1.y + o1.z * o1.z + o1.w * o1.w;
#pragma unroll
  for (int s = 32; s > 0; s >>= 1) s2 += __shfl_xor(s2, s, 64);
  f16x4 h0, h1;
  h0[0] = (_Float16)o0.x; h0[1] = (_Float16)o0.y; h0[2] = (_Float16)o0.z; h0[3] = (_Float16)o0.w;
  h1[0] = (_Float16)o1.x; h1[1] = (_Float16)o1.y; h1[2] = (_Float16)o1.z; h1[3] = (_Float16)o1.w;
  *(f16x4*)(znh + (size_t)row * D_DIM + lane * 4) = h0;
  *(f16x4*)(znh + (size_t)row * D_DIM + 256 + lane * 4) = h1;
  if (lane == 0) { znorm[row] = m; znorm2[row] = s2; }
}

__global__ __launch_bounds__(256) void prep_cb_kernel(
    const float* __restrict__ emb, float* __restrict__ cb32,
    _Float16* __restrict__ cbh, float* __restrict__ cnorm2,
    unsigned* __restrict__ counters) {
  if (blockIdx.x == 0 && threadIdx.x < 2) counters[threadIdx.x] = 0;
  const int row = blockIdx.x * 4 + ((int)threadIdx.x >> 6);
  const int lane = (int)threadIdx.x & 63;
  const float4* xr = (const float4*)(emb + (size_t)row * D_DIM);
  float4 v0 = xr[lane];
  float4 v1 = xr[lane + 64];
  float ss = v0.x * v0.x + v0.y * v0.y + v0.z * v0.z + v0.w * v0.w
           + v1.x * v1.x + v1.y * v1.y + v1.z * v1.z + v1.w * v1.w;
#pragma unroll
  for (int s = 32; s > 0; s >>= 1) ss += __shfl_xor(ss, s, 64);
  const float m = fmaxf(sqrtf(ss), EPS_NORM);
  float4 o0, o1;
  o0.x = v0.x / m; o0.y = v0.y / m; o0.z = v0.z / m; o0.w = v0.w / m;
  o1.x = v1.x / m; o1.y = v1.y / m; o1.z = v1.z / m; o1.w = v1.w / m;
  float s2 = o0.x * o0.x + o0.y * o0.y + o0.z * o0.z + o0.w * o0.w
           + o1.x * o1.x + o1.y * o1.y + o1.z * o1.z + o1.w * o1.w;
#pragma unroll
  for (int s = 32; s > 0; s >>= 1) s2 += __shfl_xor(s2, s, 64);
  float4* co = (float4*)(cb32 + (size_t)row * D_DIM);
  co[lane] = o0;
  co[lane + 64] = o1;
  f16x4 h0, h1;
  h0[0] = (_Float16)o0.x; h0[1] = (_Float16)o0.y; h0[2] = (_Float16)o0.z; h0[3] = (_Float16)o0.w;
  h1[0] = (_Float16)o1.x; h1[1] = (_Float16)o1.y; h1[2] = (_Float16)o1.z; h1[3] = (_Float16)o1.w;
  *(f16x4*)(cbh + (size_t)row * D_DIM + lane * 4) = h0;
  *(f16x4*)(cbh + (size_t)row * D_DIM + 256 + lane * 4) = h1;
  if (lane == 0) cnorm2[row] = s2;
}

// ---------------------------------------------------------------------------
// Screening GEMM v4 (m97-faithful): 128x128 tile, BK=32, 256 threads,
// 4 waves in a 2x2 grid (64x64 output per wave, acc[4][4] f32x4 in AGPRs).
// Single-buffered LDS (16 KiB -> ~3 blocks/CU for inter-block overlap),
// global_load_lds width-16 staging, both-sides XOR swizzle
// chunk = q ^ ((row>>1)&3)  -> bijective (row parity, chunk) map ->
// fully conflict-free ds_read_b128.
// Epilogue: per-row top-1 key / top-2 val per 128-col block, wave-local
// 16-lane shfl reduce + 2-wave LDS merge. K1/K2 layout identical to before.
// ---------------------------------------------------------------------------
__global__ __launch_bounds__(256) void screen_gemm_kernel(
    const _Float16* __restrict__ znh, const _Float16* __restrict__ cbh,
    u64* __restrict__ K1, unsigned* __restrict__ K2) {
  __shared__ __align__(16) _Float16 Ash[128 * 32];   // 8 KiB
  __shared__ __align__(16) _Float16 Bsh[128 * 32];   // 8 KiB
  const int tid = (int)threadIdx.x;
  const int lane = tid & 63;
  const int wv = tid >> 6;       // wave 0..3
  const int wm = wv >> 1;        // 0..1: 64-row strip
  const int wn = wv & 1;         // 0..1: 64-col strip
  const int q = lane >> 4;       // 0..3
  const int c15 = lane & 15;
  const int m0 = (int)blockIdx.y * 128;
  const int n0 = (int)blockIdx.x * 128;

  // Staging: per operand 2 global_load_lds per thread. Thread t covers
  // LDS row i*64 + (t>>2), chunk t&3; global source chunk pre-swizzled:
  // sch = (t&3) ^ ((t>>3)&3)  (== (t&3) ^ ((row>>1)&3)).
  const int srow = tid >> 2;                     // 0..63
  const int sch = (tid & 3) ^ ((tid >> 3) & 3);
  const _Float16* gA = znh + (size_t)(m0 + srow) * D_DIM + sch * 8;
  const _Float16* gB = cbh + (size_t)(n0 + srow) * D_DIM + sch * 8;

  // Read side: element offset = row*32 + (q ^ ((row>>1)&3))*8,
  // row = (w*64 + mf*16) + c15 -> (row>>1)&3 == (c15>>1)&3.
  const int rk = (q ^ ((c15 >> 1) & 3)) * 8;
  const _Float16* aBase = Ash + (wm * 64 + c15) * 32 + rk;
  const _Float16* bBase = Bsh + (wn * 64 + c15) * 32 + rk;

  f32x4 acc[4][4];
  const f32x4 z4 = {0.0f, 0.0f, 0.0f, 0.0f};
#pragma unroll
  for (int i = 0; i < 4; i++)
#pragma unroll
    for (int j = 0; j < 4; j++) acc[i][j] = z4;

  for (int kt = 0; kt < D_DIM / 32; ++kt) {
    __syncthreads();
    async_copy16(Ash + tid * 8, gA + kt * 32);
    async_copy16(Ash + 2048 + tid * 8, gA + (size_t)64 * D_DIM + kt * 32);
    async_copy16(Bsh + tid * 8, gB + kt * 32);
    async_copy16(Bsh + 2048 + tid * 8, gB + (size_t)64 * D_DIM + kt * 32);
    __syncthreads();
    f16x8 aF[4], bF[4];
#pragma unroll
    for (int i = 0; i < 4; i++) aF[i] = *(const f16x8*)(aBase + i * 16 * 32);
#pragma unroll
    for (int i = 0; i < 4; i++) bF[i] = *(const f16x8*)(bBase + i * 16 * 32);
#pragma unroll
    for (int mf = 0; mf < 4; mf++)
#pragma unroll
      for (int nf = 0; nf < 4; nf++)
        acc[mf][nf] = __builtin_amdgcn_mfma_f32_16x16x32_f16(
            aF[mf], bF[nf], acc[mf][nf], 0, 0, 0);
  }

  // -------- epilogue: top1 key / top2 val per row over this block's 128 cols
  __syncthreads();
  u64* kbuf = (u64*)Ash;                 // [128 rows][2 wn] u64 = 2 KiB
  unsigned* vbuf = (unsigned*)Bsh;       // [128 rows][2 wn] u32 = 1 KiB
#pragma unroll
  for (int mf = 0; mf < 4; ++mf) {
#pragma unroll
    for (int r = 0; r < 4; ++r) {
      u64 key1 = ~0ull;
      unsigned b2 = 0xFFFFFFFFu;
#pragma unroll
      for (int nf = 0; nf < 4; ++nf) {
        unsigned ub = orderf(-acc[mf][nf][r]);
        unsigned col = (unsigned)(n0 + wn * 64 + nf * 16 + c15);
        u64 k = ((u64)ub << 32) | (u64)col;
        unsigned v1 = (unsigned)(key1 >> 32);
        if (k < key1) { b2 = umin32(b2, v1); key1 = k; }
        else          { b2 = umin32(b2, ub); }
      }
#pragma unroll
      for (int s = 1; s <= 8; s <<= 1) {
        u64 ok = shfl_xor_u64(key1, s);
        unsigned ob2 = (unsigned)__shfl_xor((int)b2, s, 64);
        unsigned ov = (unsigned)(ok >> 32);
        unsigned v1k = (unsigned)(key1 >> 32);
        unsigned lose = (ok < key1) ? v1k : ov;
        b2 = umin32(umin32(b2, ob2), lose);
        key1 = umin64(key1, ok);
      }
      if (c15 == 0) {
        const int rowL = wm * 64 + mf * 16 + q * 4 + r;
        kbuf[rowL * 2 + wn] = key1;
        vbuf[rowL * 2 + wn] = b2;
      }
    }
  }
  __syncthreads();
  if (tid < 128) {
    u64 k0 = kbuf[tid * 2], k1 = kbuf[tid * 2 + 1];
    unsigned v0 = vbuf[tid * 2], v1 = vbuf[tid * 2 + 1];
    u64 kk = umin64(k0, k1);
    unsigned lose = (k0 < k1) ? (unsigned)(k1 >> 32) : (unsigned)(k0 >> 32);
    unsigned t2 = umin32(umin32(v0, v1), lose);
    const size_t o = (size_t)(m0 + tid) * NB + blockIdx.x;
    K1[o] = kk;
    K2[o] = t2;
  }
}

// ---------------------------------------------------------------------------
// Certify v2: one wave per row, lane = block.
//  thr = approx_top1 + MARGIN.
//  - any block with top2 <= thr, or >CAP candidates  -> heavy list (rare)
//  - exactly 1 candidate code                        -> certified, done
//  - else                                            -> light list + compact
//                                                       candidate code array
// ---------------------------------------------------------------------------
__global__ __launch_bounds__(256) void certify_kernel(
    const u64* __restrict__ K1, const unsigned* __restrict__ K2,
    unsigned* __restrict__ idx_final, unsigned* __restrict__ candList,
    unsigned* __restrict__ candCount, unsigned* __restrict__ lightList,
    unsigned* __restrict__ heavyList, unsigned* __restrict__ counters) {
  const int row = blockIdx.x * 4 + (int)(threadIdx.x >> 6);
  const int b = (int)(threadIdx.x & 63);
  u64 k = K1[(size_t)row * NB + b];
  unsigned t2 = K2[(size_t)row * NB + b];
  u64 kmin = k;
#pragma unroll
  for (int s = 1; s <= 32; s <<= 1) kmin = umin64(kmin, shfl_xor_u64(kmin, s));
  const float t1f = unorderf((unsigned)(kmin >> 32));
  const unsigned thr = orderf(t1f + MARGIN);
  const bool cand = ((unsigned)(k >> 32)) <= thr;
  const bool heavy = (t2 <= thr);
  u64 cmask = __ballot(cand);
  u64 hmask = __ballot(heavy);
  const int nc = __popcll(cmask);
  if (hmask != 0 || nc > CAP) {
    if (b == 0) {
      unsigned p = atomicAdd(counters + 1, 1u);
      heavyList[p] = (unsigned)row;
    }
  } else if (nc == 1) {
    if (b == 0) idx_final[row] = (unsigned)(kmin & 0xFFFFFFFFull);
  } else {
    if (cand) {
      int pos = __popcll(cmask & ((b == 0) ? 0ull : (~0ull >> (64 - b))));
      candList[(size_t)row * CAP + pos] = (unsigned)(k & 0xFFFFFFFFull);
    }
    if (b == 0) {
      candCount[row] = (unsigned)nc;
      unsigned p = atomicAdd(counters + 0, 1u);
      lightList[p] = (unsigned)row;
    }
  }
}

// ---------------------------------------------------------------------------
// Light rescore: one wave per flagged row; exact fp32 dist for each candidate
// code (coalesced 2KB row reads), argmin with lowest-index tie-break.
// ---------------------------------------------------------------------------
__global__ __launch_bounds__(64) void rescore_light_kernel(
    const float* __restrict__ z, const float* __restrict__ cb32,
    const float* __restrict__ znorm, const float* __restrict__ znorm2,
    const float* __restrict__ cnorm2, const unsigned* __restrict__ candList,
    const unsigned* __restrict__ candCount,
    const unsigned* __restrict__ lightList,
    const unsigned* __restrict__ counters, unsigned* __restrict__ idx_final) {
  const int lane = (int)threadIdx.x;
  const unsigned n = counters[0];
  for (unsigned i = blockIdx.x; i < n; i += gridDim.x) {
    const int row = (int)lightList[i];
    const float m = znorm[row];
    const float zn2 = znorm2[row];
    const float4* zr = (const float4*)(z + (size_t)row * D_DIM);
    float4 v0 = zr[lane], v1 = zr[lane + 64];
    float4 o0, o1;
    o0.x = v0.x / m; o0.y = v0.y / m; o0.z = v0.z / m; o0.w = v0.w / m;
    o1.x = v1.x / m; o1.y = v1.y / m; o1.z = v1.z / m; o1.w = v1.w / m;
    const unsigned nc = candCount[row];
    u64 best = ~0ull;
    for (unsigned j = 0; j < nc; j++) {
      const unsigned c = candList[(size_t)row * CAP + j];
      const float4* qr = (const float4*)(cb32 + (size_t)c * D_DIM);
      float4 q0 = qr[lane], q1 = qr[lane + 64];
      float p = o0.x * q0.x + o0.y * q0.y + o0.z * q0.z + o0.w * q0.w
              + o1.x * q1.x + o1.y * q1.y + o1.z * q1.z + o1.w * q1.w;
#pragma unroll
      for (int s = 32; s > 0; s >>= 1) p += __shfl_xor(p, s, 64);
      float dist = __fadd_rn(__fsub_rn(zn2, __fmul_rn(2.0f, p)), cnorm2[c]);
      u64 key = ((u64)orderf(dist) << 32) | (u64)c;
      best = umin64(best, key);
    }
    if (lane == 0) idx_final[row] = (unsigned)(best & 0xFFFFFFFFull);
  }
}

// ---------------------------------------------------------------------------
// Heavy rescore (rare rows): full fp32 scan of every block whose top-1 is
// within MARGIN (superset of all candidates).
// ---------------------------------------------------------------------------
__global__ __launch_bounds__(64) void rescore_heavy_kernel(
    const float* __restrict__ z, const float* __restrict__ cb32,
    const float* __restrict__ znorm, const float* __restrict__ znorm2,
    const float* __restrict__ cnorm2, const u64* __restrict__ K1,
    const unsigned* __restrict__ heavyList,
    const unsigned* __restrict__ counters, unsigned* __restrict__ idx_final) {
  __shared__ float znl[D_DIM];
  const int lane = (int)threadIdx.x;
  const unsigned n = counters[1];
  for (unsigned i = blockIdx.x; i < n; i += gridDim.x) {
    const int row = (int)heavyList[i];
    const float m = znorm[row];
    const float4* zr = (const float4*)(z + (size_t)row * D_DIM);
    float4 v0 = zr[lane], v1 = zr[lane + 64];
    __syncthreads();
    float4 o0, o1;
    o0.x = v0.x / m; o0.y = v0.y / m; o0.z = v0.z / m; o0.w = v0.w / m;
    o1.x = v1.x / m; o1.y = v1.y / m; o1.z = v1.z / m; o1.w = v1.w / m;
    *(float4*)&znl[lane * 4] = o0;
    *(float4*)&znl[256 + lane * 4] = o1;
    u64 k = K1[(size_t)row * NB + lane];
    u64 kmin = k;
#pragma unroll
    for (int s = 1; s <= 32; s <<= 1) kmin = umin64(kmin, shfl_xor_u64(kmin, s));
    const float t1 = unorderf((unsigned)(kmin >> 32));
    const bool cf = unorderf((unsigned)(k >> 32)) <= t1 + MARGIN;
    u64 mask = __ballot(cf);
    __syncthreads();
    const float zn2 = znorm2[row];
    u64 best = ~0ull;
    while (mask) {
      const int b = __builtin_ctzll(mask);
      mask &= mask - 1;
#pragma unroll
      for (int h = 0; h < 2; h++) {
        const int c = b * 128 + h * 64 + lane;
        const float4* cr = (const float4*)(cb32 + (size_t)c * D_DIM);
        float dot = 0.0f;
        for (int d = 0; d < 128; d++) {
          float4 bb = cr[d];
          float4 aa = *(const float4*)&znl[d * 4];
          dot = __fmaf_rn(aa.x, bb.x, dot);
          dot = __fmaf_rn(aa.y, bb.y, dot);
          dot = __fmaf_rn(aa.z, bb.z, dot);
          dot = __fmaf_rn(aa.w, bb.w, dot);
        }
        float dist = __fadd_rn(__fsub_rn(zn2, __fmul_rn(2.0f, dot)), cnorm2[c]);
        u64 key = ((u64)orderf(dist) << 32) | (u64)(unsigned)c;
        best = umin64(best, key);
      }
    }
#pragma unroll
    for (int s = 1; s <= 32; s <<= 1) best = umin64(best, shfl_xor_u64(best, s));
    if (lane == 0) idx_final[row] = (unsigned)(best & 0xFFFFFFFFull);
  }
}

// ---------------------------------------------------------------------------
// Finalize: gather code, project, write outputs. 4 rows per 256-thread block.
// ---------------------------------------------------------------------------
__global__ __launch_bounds__(256) void finalize_kernel(
    const float* __restrict__ z, const float* __restrict__ cb32,
    const float* __restrict__ znorm, const unsigned* __restrict__ idx_final,
    float* __restrict__ out) {
  const int row = blockIdx.x * 4 + ((int)threadIdx.x >> 6);
  const int lane = (int)threadIdx.x & 63;
  const float m = znorm[row];
  const unsigned idx = idx_final[row];
  const float4* zr = (const float4*)(z + (size_t)row * D_DIM);
  const float4* qr = (const float4*)(cb32 + (size_t)idx * D_DIM);
  float4 v0 = zr[lane], v1 = zr[lane + 64];
  float4 q0 = qr[lane], q1 = qr[lane + 64];
  float4 z0, z1;
  z0.x = v0.x / m; z0.y = v0.y / m; z0.z = v0.z / m; z0.w = v0.w / m;
  z1.x = v1.x / m; z1.y = v1.y / m; z1.z = v1.z / m; z1.w = v1.w / m;
  float p = z0.x * q0.x + z0.y * q0.y + z0.z * q0.z + z0.w * q0.w
          + z1.x * q1.x + z1.y * q1.y + z1.z * q1.z + z1.w * q1.w;
#pragma unroll
  for (int s = 32; s > 0; s >>= 1) p += __shfl_xor(p, s, 64);
  float4 o0, o1;
  o0.x = p * q0.x; o0.y = p * q0.y; o0.z = p * q0.z; o0.w = p * q0.w;
  o1.x = p * q1.x; o1.y = p * q1.y; o1.z = p * q1.z; o1.w = p * q1.w;
  float4* orow = (float4*)(out + (size_t)row * D_DIM);
  orow[lane] = o0;
  orow[lane + 64] = o1;
  if (lane == 0) out[(size_t)N_ROWS * D_DIM + row] = (float)idx;
}

// ---------------------------------------------------------------------------
extern "C" void kernel_launch(void* const* d_in, const int* in_sizes, int n_in,
                              void* d_out, int out_size, void* d_ws,
                              size_t ws_size, hipStream_t stream) {
  const float* z = (const float*)d_in[0];
  const float* emb = (const float*)d_in[1];
  float* out = (float*)d_out;

  // ws layout, ~142 MB total:
  u64* K1 = (u64*)d_ws;                                   // 32 MB
  unsigned* K2 = (unsigned*)(K1 + (size_t)N_ROWS * NB);   // 16 MB
  float* cb32 = (float*)(K2 + (size_t)N_ROWS * NB);       // 16 MB
  float* znorm = cb32 + (size_t)K_CODES * D_DIM;          // 256 KB
  float* znorm2 = znorm + N_ROWS;                         // 256 KB
  float* cnorm2 = znorm2 + N_ROWS;                        // 32 KB
  unsigned* idx_final = (unsigned*)(cnorm2 + K_CODES);    // 256 KB
  unsigned* lightList = idx_final + N_ROWS;               // 256 KB
  unsigned* heavyList = lightList + N_ROWS;               // 256 KB
  unsigned* candCount = heavyList + N_ROWS;               // 256 KB
  unsigned* counters = candCount + N_ROWS;                // 64*4 pad
  unsigned* candList = counters + 64;                     // 4 MB
  _Float16* znh = (_Float16*)(candList + (size_t)N_ROWS * CAP);  // 64 MB
  _Float16* cbh = znh + (size_t)N_ROWS * D_DIM;           // 8 MB

  prep_z_kernel<<<N_ROWS / 4, 256, 0, stream>>>(z, znh, znorm, znorm2);
  prep_cb_kernel<<<K_CODES / 4, 256, 0, stream>>>(emb, cb32, cbh, cnorm2,
                                                  counters);

  dim3 grid(K_CODES / 128, N_ROWS / 128);   // (64, 512)
  screen_gemm_kernel<<<grid, 256, 0, stream>>>(znh, cbh, K1, K2);

  certify_kernel<<<N_ROWS / 4, 256, 0, stream>>>(
      K1, K2, idx_final, candList, candCount, lightList, heavyList, counters);
  rescore_light_kernel<<<8192, 64, 0, stream>>>(
      z, cb32, znorm, znorm2, cnorm2, candList, candCount, lightList, counters,
      idx_final);
  rescore_heavy_kernel<<<512, 64, 0, stream>>>(
      z, cb32, znorm, znorm2, cnorm2, K1, heavyList, counters, idx_final);
  finalize_kernel<<<N_ROWS / 4, 256, 0, stream>>>(z, cb32, znorm, idx_final,
                                                  out);
}

// Round 3
// 1254.962 us; speedup vs baseline: 1.1636x; 1.1124x over previous
//
#include <hip/hip_runtime.h>
#include <stdint.h>

#define N_ROWS 65536
#define K_CODES 8192
#define D_DIM 512
#define EPS_NORM 1e-12f
#define NB 64            // number of 128-wide column blocks
#define MARGIN 2.5e-3f   // > 2x hard bound on fp16 dot error (2*1.01e-3)
#define CAP 16           // max per-row candidate codes on the light path

typedef _Float16 f16x8 __attribute__((ext_vector_type(8)));
typedef _Float16 f16x4 __attribute__((ext_vector_type(4)));
typedef float f32x4 __attribute__((ext_vector_type(4)));
typedef unsigned long long u64;

__device__ __forceinline__ unsigned orderf(float f) {
  unsigned u = __float_as_uint(f);
  return (u & 0x80000000u) ? ~u : (u | 0x80000000u);
}
__device__ __forceinline__ float unorderf(unsigned ub) {
  unsigned u = (ub & 0x80000000u) ? (ub & 0x7FFFFFFFu) : ~ub;
  return __uint_as_float(u);
}
__device__ __forceinline__ unsigned umin32(unsigned a, unsigned b) { return a < b ? a : b; }
__device__ __forceinline__ u64 umin64(u64 a, u64 b) { return a < b ? a : b; }
__device__ __forceinline__ u64 shfl_xor_u64(u64 v, int m) {
  unsigned lo = (unsigned)__shfl_xor((int)(unsigned)(v & 0xFFFFFFFFull), m, 64);
  unsigned hi = (unsigned)__shfl_xor((int)(unsigned)(v >> 32), m, 64);
  return ((u64)hi << 32) | (u64)lo;
}
__device__ __forceinline__ void async_copy16(void* lds, const void* g) {
  __builtin_amdgcn_global_load_lds(
      (const __attribute__((address_space(1))) void*)g,
      (__attribute__((address_space(3))) void*)lds, 16, 0, 0);
}

// ---------------------------------------------------------------------------
// prep: L2-normalize rows (F.normalize semantics), emit fp16 copy for MFMA.
// 4 rows per 256-thread block. prep_z uses rm-multiply (argmin-safe: all
// exact-path consumers re-divide raw z; znorm2 shift is row-constant).
// ---------------------------------------------------------------------------
__global__ __launch_bounds__(256) void prep_z_kernel(
    const float* __restrict__ z, _Float16* __restrict__ znh,
    float* __restrict__ znorm, float* __restrict__ znorm2) {
  const int row = blockIdx.x * 4 + ((int)threadIdx.x >> 6);
  const int lane = (int)threadIdx.x & 63;
  const float4* xr = (const float4*)(z + (size_t)row * D_DIM);
  float4 v0 = xr[lane];
  float4 v1 = xr[lane + 64];
  float ss = v0.x * v0.x + v0.y * v0.y + v0.z * v0.z + v0.w * v0.w
           + v1.x * v1.x + v1.y * v1.y + v1.z * v1.z + v1.w * v1.w;
#pragma unroll
  for (int s = 32; s > 0; s >>= 1) ss += __shfl_xor(ss, s, 64);
  const float m = fmaxf(sqrtf(ss), EPS_NORM);
  const float rm = 1.0f / m;
  float4 o0, o1;
  o0.x = v0.x * rm; o0.y = v0.y * rm; o0.z = v0.z * rm; o0.w = v0.w * rm;
  o1.x = v1.x * rm; o1.y = v1.y * rm; o1.z = v1.z * rm; o1.w = v1.w * rm;
  float s2 = o0.x * o0.x + o0.y * o0.y + o0.z * o0.z + o0.w * o0.w
           + o1.x * o1.x + o1.y * o1.y + o1.z * o1.z + o1.w * o1.w;
#pragma unroll
  for (int s = 32; s > 0; s >>= 1) s2 += __shfl_xor(s2, s, 64);
  f16x4 h0, h1;
  h0[0] = (_Float16)o0.x; h0[1] = (_Float16)o0.y; h0[2] = (_Float16)o0.z; h0[3] = (_Float16)o0.w;
  h1[0] = (_Float16)o1.x; h1[1] = (_Float16)o1.y; h1[2] = (_Float16)o1.z; h1[3] = (_Float16)o1.w;
  *(f16x4*)(znh + (size_t)row * D_DIM + lane * 4) = h0;
  *(f16x4*)(znh + (size_t)row * D_DIM + 256 + lane * 4) = h1;
  if (lane == 0) { znorm[row] = m; znorm2[row] = s2; }
}

__global__ __launch_bounds__(256) void prep_cb_kernel(
    const float* __restrict__ emb, float* __restrict__ cb32,
    _Float16* __restrict__ cbh, float* __restrict__ cnorm2,
    unsigned* __restrict__ counters) {
  if (blockIdx.x == 0 && threadIdx.x < 2) counters[threadIdx.x] = 0;
  const int row = blockIdx.x * 4 + ((int)threadIdx.x >> 6);
  const int lane = (int)threadIdx.x & 63;
  const float4* xr = (const float4*)(emb + (size_t)row * D_DIM);
  float4 v0 = xr[lane];
  float4 v1 = xr[lane + 64];
  float ss = v0.x * v0.x + v0.y * v0.y + v0.z * v0.z + v0.w * v0.w
           + v1.x * v1.x + v1.y * v1.y + v1.z * v1.z + v1.w * v1.w;
#pragma unroll
  for (int s = 32; s > 0; s >>= 1) ss += __shfl_xor(ss, s, 64);
  const float m = fmaxf(sqrtf(ss), EPS_NORM);
  float4 o0, o1;
  o0.x = v0.x / m; o0.y = v0.y / m; o0.z = v0.z / m; o0.w = v0.w / m;
  o1.x = v1.x / m; o1.y = v1.y / m; o1.z = v1.z / m; o1.w = v1.w / m;
  float s2 = o0.x * o0.x + o0.y * o0.y + o0.z * o0.z + o0.w * o0.w
           + o1.x * o1.x + o1.y * o1.y + o1.z * o1.z + o1.w * o1.w;
#pragma unroll
  for (int s = 32; s > 0; s >>= 1) s2 += __shfl_xor(s2, s, 64);
  float4* co = (float4*)(cb32 + (size_t)row * D_DIM);
  co[lane] = o0;
  co[lane + 64] = o1;
  f16x4 h0, h1;
  h0[0] = (_Float16)o0.x; h0[1] = (_Float16)o0.y; h0[2] = (_Float16)o0.z; h0[3] = (_Float16)o0.w;
  h1[0] = (_Float16)o1.x; h1[1] = (_Float16)o1.y; h1[2] = (_Float16)o1.z; h1[3] = (_Float16)o1.w;
  *(f16x4*)(cbh + (size_t)row * D_DIM + lane * 4) = h0;
  *(f16x4*)(cbh + (size_t)row * D_DIM + 256 + lane * 4) = h1;
  if (lane == 0) cnorm2[row] = s2;
}

// ---------------------------------------------------------------------------
// Screening GEMM v5: 128x128 tile, BK=32, 2x2 wave grid, triple-buffered
// LDS (48 KiB) with depth-2 prefetch and counted vmcnt(4) (T3+T4 minimum).
// Swapped-operand MFMA (cb as A, zn as B) puts the N-index into (q,r) ->
// lane-local 16-value top1/top2 scan + only 2 shuffle steps (was 4).
// XCD-chunked block swizzle: each XCD owns 64 consecutive m-panels with
// n fastest -> K1/K2 64B-line write merging in its private L2 + znh reuse.
// Both-sides XOR swizzle keeps ds_read_b128 conflict-free.
// ---------------------------------------------------------------------------
#define LGKM0 asm volatile("s_waitcnt lgkmcnt(0)" ::: "memory")
#define VM4 asm volatile("s_waitcnt vmcnt(4)" ::: "memory")
#define VM0 asm volatile("s_waitcnt vmcnt(0)" ::: "memory")
#define BARF                                                                  \
  do { asm volatile("" ::: "memory"); __builtin_amdgcn_s_barrier();           \
       asm volatile("" ::: "memory"); } while (0)

#define STAGE(b, kt)                                                          \
  do {                                                                        \
    async_copy16(lds + (b) * 8192 + tid * 8,        gZ  + (kt) * 32);         \
    async_copy16(lds + (b) * 8192 + 2048 + tid * 8, gZ2 + (kt) * 32);         \
    async_copy16(lds + (b) * 8192 + 4096 + tid * 8, gC  + (kt) * 32);         \
    async_copy16(lds + (b) * 8192 + 6144 + tid * 8, gC2 + (kt) * 32);         \
  } while (0)

#define COMPUTE(b)                                                            \
  do {                                                                        \
    f16x8 zF[4], cF[4];                                                       \
    _Pragma("unroll") for (int mf_ = 0; mf_ < 4; ++mf_)                       \
      zF[mf_] = *(const f16x8*)(zRd + (b) * 8192 + mf_ * 512);                \
    _Pragma("unroll") for (int nf_ = 0; nf_ < 4; ++nf_)                       \
      cF[nf_] = *(const f16x8*)(cRd + (b) * 8192 + nf_ * 512);                \
    LGKM0;                                                                    \
    __builtin_amdgcn_sched_barrier(0);                                        \
    _Pragma("unroll") for (int nf_ = 0; nf_ < 4; ++nf_)                       \
      _Pragma("unroll") for (int mf_ = 0; mf_ < 4; ++mf_)                     \
        acc[nf_][mf_] = __builtin_amdgcn_mfma_f32_16x16x32_f16(               \
            cF[nf_], zF[mf_], acc[nf_][mf_], 0, 0, 0);                        \
  } while (0)

__global__ __launch_bounds__(256, 3) void screen_gemm_kernel(
    const _Float16* __restrict__ znh, const _Float16* __restrict__ cbh,
    u64* __restrict__ K1, unsigned* __restrict__ K2) {
  __shared__ __align__(16) _Float16 lds[24576];  // 3 x (Z 8KB | C 8KB)
  const int tid = (int)threadIdx.x;
  const int lane = tid & 63;
  const int wv = tid >> 6;       // wave 0..3
  const int wm = wv >> 1;        // 0..1: 64-row (M) strip
  const int wn = wv & 1;         // 0..1: 64-col (N) strip
  const int q = lane >> 4;       // 0..3
  const int c15 = lane & 15;

  // XCD-chunked swizzle (32768 blocks, 8 XCDs, round-robin by linear id).
  const int o = (int)blockIdx.x;
  const int l = (o & 7) * 4096 + (o >> 3);
  const int bx = l & 63;         // n-block
  const int by = l >> 6;         // m-block
  const int m0 = by * 128;
  const int n0 = bx * 128;

  // Staging sources (chunk-XOR pre-swizzled, linear LDS dest):
  const int srow = tid >> 2;                     // 0..63
  const int sch = (tid & 3) ^ ((tid >> 3) & 3);
  const _Float16* gZ  = znh + (size_t)(m0 + srow) * D_DIM + sch * 8;
  const _Float16* gZ2 = gZ + (size_t)64 * D_DIM;
  const _Float16* gC  = cbh + (size_t)(n0 + srow) * D_DIM + sch * 8;
  const _Float16* gC2 = gC + (size_t)64 * D_DIM;

  // Read side: element k-offset = (q ^ ((row>>1)&3))*8, row parity from c15.
  const int rk = (q ^ ((c15 >> 1) & 3)) * 8;
  const _Float16* zRd = lds + (wm * 64 + c15) * 32 + rk;          // Z region
  const _Float16* cRd = lds + 4096 + (wn * 64 + c15) * 32 + rk;   // C region

  f32x4 acc[4][4];   // acc[nf][mf]: M = wm*64+mf*16+c15, N = wn*64+nf*16+q*4+r
  const f32x4 z4 = {0.0f, 0.0f, 0.0f, 0.0f};
#pragma unroll
  for (int i = 0; i < 4; i++)
#pragma unroll
    for (int j = 0; j < 4; j++) acc[i][j] = z4;

  // ---- depth-2 pipelined K-loop, 16 tiles, fully static buffers ----
  STAGE(0, 0); STAGE(1, 1);
  VM4; BARF;
  STAGE(2, 2);  COMPUTE(0); VM4; BARF;
  STAGE(0, 3);  COMPUTE(1); VM4; BARF;
  STAGE(1, 4);  COMPUTE(2); VM4; BARF;
  STAGE(2, 5);  COMPUTE(0); VM4; BARF;
  STAGE(0, 6);  COMPUTE(1); VM4; BARF;
  STAGE(1, 7);  COMPUTE(2); VM4; BARF;
  STAGE(2, 8);  COMPUTE(0); VM4; BARF;
  STAGE(0, 9);  COMPUTE(1); VM4; BARF;
  STAGE(1, 10); COMPUTE(2); VM4; BARF;
  STAGE(2, 11); COMPUTE(0); VM4; BARF;
  STAGE(0, 12); COMPUTE(1); VM4; BARF;
  STAGE(1, 13); COMPUTE(2); VM4; BARF;
  STAGE(2, 14); COMPUTE(0); VM4; BARF;
  STAGE(0, 15); COMPUTE(1); VM4; BARF;
  COMPUTE(2); VM0; BARF;
  COMPUTE(0);

  // ---- epilogue: lane-local top1/top2 over 16 N-values, 2 shfl steps ----
  __syncthreads();
  u64* kbuf = (u64*)lds;                       // [128 rows][2 wn] u64 = 2KB
  unsigned* vbuf = (unsigned*)(lds + 1024);    // bytes 2048..3071
#pragma unroll
  for (int mf = 0; mf < 4; ++mf) {
    float v1 = __builtin_inff(), v2 = __builtin_inff();
    int c1 = 0;
#pragma unroll
    for (int nf = 0; nf < 4; ++nf)
#pragma unroll
      for (int r = 0; r < 4; ++r) {
        float v = -acc[nf][mf][r];
        int col = n0 + wn * 64 + nf * 16 + q * 4 + r;
        if (v < v1) { v2 = v1; v1 = v; c1 = col; }
        else        { v2 = fminf(v2, v); }
      }
    u64 key1 = ((u64)orderf(v1) << 32) | (u64)(unsigned)c1;
    unsigned b2 = orderf(v2);
#pragma unroll
    for (int s = 16; s <= 32; s <<= 1) {
      u64 ok = shfl_xor_u64(key1, s);
      unsigned ob2 = (unsigned)__shfl_xor((int)b2, s, 64);
      unsigned ov = (unsigned)(ok >> 32);
      unsigned v1k = (unsigned)(key1 >> 32);
      unsigned lose = (ok < key1) ? v1k : ov;
      b2 = umin32(umin32(b2, ob2), lose);
      key1 = umin64(key1, ok);
    }
    if (q == 0) {
      const int rowL = wm * 64 + mf * 16 + c15;
      kbuf[rowL * 2 + wn] = key1;
      vbuf[rowL * 2 + wn] = b2;
    }
  }
  __syncthreads();
  if (tid < 128) {
    u64 k0 = kbuf[tid * 2], k1v = kbuf[tid * 2 + 1];
    unsigned v0 = vbuf[tid * 2], v1 = vbuf[tid * 2 + 1];
    u64 kk = umin64(k0, k1v);
    unsigned lose = (k0 < k1v) ? (unsigned)(k1v >> 32) : (unsigned)(k0 >> 32);
    unsigned t2 = umin32(umin32(v0, v1), lose);
    const size_t oo = (size_t)(m0 + tid) * NB + bx;
    K1[oo] = kk;
    K2[oo] = t2;
  }
}

// ---------------------------------------------------------------------------
// Certify v2: one wave per row, lane = block.
//  thr = approx_top1 + MARGIN.
//  - any block with top2 <= thr, or >CAP candidates  -> heavy list (rare)
//  - exactly 1 candidate code                        -> certified, done
//  - else                                            -> light list + compact
//                                                       candidate code array
// ---------------------------------------------------------------------------
__global__ __launch_bounds__(256) void certify_kernel(
    const u64* __restrict__ K1, const unsigned* __restrict__ K2,
    unsigned* __restrict__ idx_final, unsigned* __restrict__ candList,
    unsigned* __restrict__ candCount, unsigned* __restrict__ lightList,
    unsigned* __restrict__ heavyList, unsigned* __restrict__ counters) {
  const int row = blockIdx.x * 4 + (int)(threadIdx.x >> 6);
  const int b = (int)(threadIdx.x & 63);
  u64 k = K1[(size_t)row * NB + b];
  unsigned t2 = K2[(size_t)row * NB + b];
  u64 kmin = k;
#pragma unroll
  for (int s = 1; s <= 32; s <<= 1) kmin = umin64(kmin, shfl_xor_u64(kmin, s));
  const float t1f = unorderf((unsigned)(kmin >> 32));
  const unsigned thr = orderf(t1f + MARGIN);
  const bool cand = ((unsigned)(k >> 32)) <= thr;
  const bool heavy = (t2 <= thr);
  u64 cmask = __ballot(cand);
  u64 hmask = __ballot(heavy);
  const int nc = __popcll(cmask);
  if (hmask != 0 || nc > CAP) {
    if (b == 0) {
      unsigned p = atomicAdd(counters + 1, 1u);
      heavyList[p] = (unsigned)row;
    }
  } else if (nc == 1) {
    if (b == 0) idx_final[row] = (unsigned)(kmin & 0xFFFFFFFFull);
  } else {
    if (cand) {
      int pos = __popcll(cmask & ((b == 0) ? 0ull : (~0ull >> (64 - b))));
      candList[(size_t)row * CAP + pos] = (unsigned)(k & 0xFFFFFFFFull);
    }
    if (b == 0) {
      candCount[row] = (unsigned)nc;
      unsigned p = atomicAdd(counters + 0, 1u);
      lightList[p] = (unsigned)row;
    }
  }
}

// ---------------------------------------------------------------------------
// Light rescore: one wave per flagged row; exact fp32 dist for each candidate
// code (coalesced 2KB row reads), argmin with lowest-index tie-break.
// ---------------------------------------------------------------------------
__global__ __launch_bounds__(64) void rescore_light_kernel(
    const float* __restrict__ z, const float* __restrict__ cb32,
    const float* __restrict__ znorm, const float* __restrict__ znorm2,
    const float* __restrict__ cnorm2, const unsigned* __restrict__ candList,
    const unsigned* __restrict__ candCount,
    const unsigned* __restrict__ lightList,
    const unsigned* __restrict__ counters, unsigned* __restrict__ idx_final) {
  const int lane = (int)threadIdx.x;
  const unsigned n = counters[0];
  for (unsigned i = blockIdx.x; i < n; i += gridDim.x) {
    const int row = (int)lightList[i];
    const float m = znorm[row];
    const float zn2 = znorm2[row];
    const float4* zr = (const float4*)(z + (size_t)row * D_DIM);
    float4 v0 = zr[lane], v1 = zr[lane + 64];
    float4 o0, o1;
    o0.x = v0.x / m; o0.y = v0.y / m; o0.z = v0.z / m; o0.w = v0.w / m;
    o1.x = v1.x / m; o1.y = v1.y / m; o1.z = v1.z / m; o1.w = v1.w / m;
    const unsigned nc = candCount[row];
    u64 best = ~0ull;
    for (unsigned j = 0; j < nc; j++) {
      const unsigned c = candList[(size_t)row * CAP + j];
      const float4* qr = (const float4*)(cb32 + (size_t)c * D_DIM);
      float4 q0 = qr[lane], q1 = qr[lane + 64];
      float p = o0.x * q0.x + o0.y * q0.y + o0.z * q0.z + o0.w * q0.w
              + o1.x * q1.x + o1.y * q1.y + o1.z * q1.z + o1.w * q1.w;
#pragma unroll
      for (int s = 32; s > 0; s >>= 1) p += __shfl_xor(p, s, 64);
      float dist = __fadd_rn(__fsub_rn(zn2, __fmul_rn(2.0f, p)), cnorm2[c]);
      u64 key = ((u64)orderf(dist) << 32) | (u64)c;
      best = umin64(best, key);
    }
    if (lane == 0) idx_final[row] = (unsigned)(best & 0xFFFFFFFFull);
  }
}

// ---------------------------------------------------------------------------
// Heavy rescore (rare rows): full fp32 scan of every block whose top-1 is
// within MARGIN (superset of all candidates).
// ---------------------------------------------------------------------------
__global__ __launch_bounds__(64) void rescore_heavy_kernel(
    const float* __restrict__ z, const float* __restrict__ cb32,
    const float* __restrict__ znorm, const float* __restrict__ znorm2,
    const float* __restrict__ cnorm2, const u64* __restrict__ K1,
    const unsigned* __restrict__ heavyList,
    const unsigned* __restrict__ counters, unsigned* __restrict__ idx_final) {
  __shared__ float znl[D_DIM];
  const int lane = (int)threadIdx.x;
  const unsigned n = counters[1];
  for (unsigned i = blockIdx.x; i < n; i += gridDim.x) {
    const int row = (int)heavyList[i];
    const float m = znorm[row];
    const float4* zr = (const float4*)(z + (size_t)row * D_DIM);
    float4 v0 = zr[lane], v1 = zr[lane + 64];
    __syncthreads();
    float4 o0, o1;
    o0.x = v0.x / m; o0.y = v0.y / m; o0.z = v0.z / m; o0.w = v0.w / m;
    o1.x = v1.x / m; o1.y = v1.y / m; o1.z = v1.z / m; o1.w = v1.w / m;
    *(float4*)&znl[lane * 4] = o0;
    *(float4*)&znl[256 + lane * 4] = o1;
    u64 k = K1[(size_t)row * NB + lane];
    u64 kmin = k;
#pragma unroll
    for (int s = 1; s <= 32; s <<= 1) kmin = umin64(kmin, shfl_xor_u64(kmin, s));
    const float t1 = unorderf((unsigned)(kmin >> 32));
    const bool cf = unorderf((unsigned)(k >> 32)) <= t1 + MARGIN;
    u64 mask = __ballot(cf);
    __syncthreads();
    const float zn2 = znorm2[row];
    u64 best = ~0ull;
    while (mask) {
      const int b = __builtin_ctzll(mask);
      mask &= mask - 1;
#pragma unroll
      for (int h = 0; h < 2; h++) {
        const int c = b * 128 + h * 64 + lane;
        const float4* cr = (const float4*)(cb32 + (size_t)c * D_DIM);
        float dot = 0.0f;
        for (int d = 0; d < 128; d++) {
          float4 bb = cr[d];
          float4 aa = *(const float4*)&znl[d * 4];
          dot = __fmaf_rn(aa.x, bb.x, dot);
          dot = __fmaf_rn(aa.y, bb.y, dot);
          dot = __fmaf_rn(aa.z, bb.z, dot);
          dot = __fmaf_rn(aa.w, bb.w, dot);
        }
        float dist = __fadd_rn(__fsub_rn(zn2, __fmul_rn(2.0f, dot)), cnorm2[c]);
        u64 key = ((u64)orderf(dist) << 32) | (u64)(unsigned)c;
        best = umin64(best, key);
      }
    }
#pragma unroll
    for (int s = 1; s <= 32; s <<= 1) best = umin64(best, shfl_xor_u64(best, s));
    if (lane == 0) idx_final[row] = (unsigned)(best & 0xFFFFFFFFull);
  }
}

// ---------------------------------------------------------------------------
// Finalize: gather code, project, write outputs. 4 rows per 256-thread block.
// ---------------------------------------------------------------------------
__global__ __launch_bounds__(256) void finalize_kernel(
    const float* __restrict__ z, const float* __restrict__ cb32,
    const float* __restrict__ znorm, const unsigned* __restrict__ idx_final,
    float* __restrict__ out) {
  const int row = blockIdx.x * 4 + ((int)threadIdx.x >> 6);
  const int lane = (int)threadIdx.x & 63;
  const float m = znorm[row];
  const unsigned idx = idx_final[row];
  const float4* zr = (const float4*)(z + (size_t)row * D_DIM);
  const float4* qr = (const float4*)(cb32 + (size_t)idx * D_DIM);
  float4 v0 = zr[lane], v1 = zr[lane + 64];
  float4 q0 = qr[lane], q1 = qr[lane + 64];
  float4 z0, z1;
  z0.x = v0.x / m; z0.y = v0.y / m; z0.z = v0.z / m; z0.w = v0.w / m;
  z1.x = v1.x / m; z1.y = v1.y / m; z1.z = v1.z / m; z1.w = v1.w / m;
  float p = z0.x * q0.x + z0.y * q0.y + z0.z * q0.z + z0.w * q0.w
          + z1.x * q1.x + z1.y * q1.y + z1.z * q1.z + z1.w * q1.w;
#pragma unroll
  for (int s = 32; s > 0; s >>= 1) p += __shfl_xor(p, s, 64);
  float4 o0, o1;
  o0.x = p * q0.x; o0.y = p * q0.y; o0.z = p * q0.z; o0.w = p * q0.w;
  o1.x = p * q1.x; o1.y = p * q1.y; o1.z = p * q1.z; o1.w = p * q1.w;
  float4* orow = (float4*)(out + (size_t)row * D_DIM);
  orow[lane] = o0;
  orow[lane + 64] = o1;
  if (lane == 0) out[(size_t)N_ROWS * D_DIM + row] = (float)idx;
}

// ---------------------------------------------------------------------------
extern "C" void kernel_launch(void* const* d_in, const int* in_sizes, int n_in,
                              void* d_out, int out_size, void* d_ws,
                              size_t ws_size, hipStream_t stream) {
  const float* z = (const float*)d_in[0];
  const float* emb = (const float*)d_in[1];
  float* out = (float*)d_out;

  // ws layout, ~142 MB total:
  u64* K1 = (u64*)d_ws;                                   // 32 MB
  unsigned* K2 = (unsigned*)(K1 + (size_t)N_ROWS * NB);   // 16 MB
  float* cb32 = (float*)(K2 + (size_t)N_ROWS * NB);       // 16 MB
  float* znorm = cb32 + (size_t)K_CODES * D_DIM;          // 256 KB
  float* znorm2 = znorm + N_ROWS;                         // 256 KB
  float* cnorm2 = znorm2 + N_ROWS;                        // 32 KB
  unsigned* idx_final = (unsigned*)(cnorm2 + K_CODES);    // 256 KB
  unsigned* lightList = idx_final + N_ROWS;               // 256 KB
  unsigned* heavyList = lightList + N_ROWS;               // 256 KB
  unsigned* candCount = heavyList + N_ROWS;               // 256 KB
  unsigned* counters = candCount + N_ROWS;                // 64*4 pad
  unsigned* candList = counters + 64;                     // 4 MB
  _Float16* znh = (_Float16*)(candList + (size_t)N_ROWS * CAP);  // 64 MB
  _Float16* cbh = znh + (size_t)N_ROWS * D_DIM;           // 8 MB

  prep_z_kernel<<<N_ROWS / 4, 256, 0, stream>>>(z, znh, znorm, znorm2);
  prep_cb_kernel<<<K_CODES / 4, 256, 0, stream>>>(emb, cb32, cbh, cnorm2,
                                                  counters);

  screen_gemm_kernel<<<32768, 256, 0, stream>>>(znh, cbh, K1, K2);

  certify_kernel<<<N_ROWS / 4, 256, 0, stream>>>(
      K1, K2, idx_final, candList, candCount, lightList, heavyList, counters);
  rescore_light_kernel<<<8192, 64, 0, stream>>>(
      z, cb32, znorm, znorm2, cnorm2, candList, candCount, lightList, counters,
      idx_final);
  rescore_heavy_kernel<<<512, 64, 0, stream>>>(
      z, cb32, znorm, znorm2, cnorm2, K1, heavyList, counters, idx_final);
  finalize_kernel<<<N_ROWS / 4, 256, 0, stream>>>(z, cb32, znorm, idx_final,
                                                  out);
}

// Round 6
// 1238.704 us; speedup vs baseline: 1.1789x; 1.0131x over previous
//
#include <hip/hip_runtime.h>
#include <stdint.h>

#define N_ROWS 65536
#define K_CODES 8192
#define D_DIM 512
#define EPS_NORM 1e-12f
#define NB 64            // number of 128-wide column blocks
#define MARGIN 2.5e-3f   // > 2x hard bound on fp16 dot error (2*1.01e-3)
#define CAP 16           // max per-row candidate codes on the light path

typedef _Float16 f16x8 __attribute__((ext_vector_type(8)));
typedef _Float16 f16x4 __attribute__((ext_vector_type(4)));
typedef float f32x4 __attribute__((ext_vector_type(4)));
typedef unsigned long long u64;

__device__ __forceinline__ unsigned orderf(float f) {
  unsigned u = __float_as_uint(f);
  return (u & 0x80000000u) ? ~u : (u | 0x80000000u);
}
__device__ __forceinline__ float unorderf(unsigned ub) {
  unsigned u = (ub & 0x80000000u) ? (ub & 0x7FFFFFFFu) : ~ub;
  return __uint_as_float(u);
}
__device__ __forceinline__ unsigned umin32(unsigned a, unsigned b) { return a < b ? a : b; }
__device__ __forceinline__ u64 umin64(u64 a, u64 b) { return a < b ? a : b; }
__device__ __forceinline__ u64 shfl_xor_u64(u64 v, int m) {
  unsigned lo = (unsigned)__shfl_xor((int)(unsigned)(v & 0xFFFFFFFFull), m, 64);
  unsigned hi = (unsigned)__shfl_xor((int)(unsigned)(v >> 32), m, 64);
  return ((u64)hi << 32) | (u64)lo;
}
__device__ __forceinline__ void async_copy16(void* lds, const void* g) {
  __builtin_amdgcn_global_load_lds(
      (const __attribute__((address_space(1))) void*)g,
      (__attribute__((address_space(3))) void*)lds, 16, 0, 0);
}

// ---------------------------------------------------------------------------
// prep: L2-normalize rows (F.normalize semantics), emit fp16 copy for MFMA.
// 4 rows per 256-thread block. prep_z uses rm-multiply (argmin-safe: all
// exact-path consumers re-divide raw z; znorm2 shift is row-constant).
// ---------------------------------------------------------------------------
__global__ __launch_bounds__(256) void prep_z_kernel(
    const float* __restrict__ z, _Float16* __restrict__ znh,
    float* __restrict__ znorm, float* __restrict__ znorm2) {
  const int row = blockIdx.x * 4 + ((int)threadIdx.x >> 6);
  const int lane = (int)threadIdx.x & 63;
  const float4* xr = (const float4*)(z + (size_t)row * D_DIM);
  float4 v0 = xr[lane];
  float4 v1 = xr[lane + 64];
  float ss = v0.x * v0.x + v0.y * v0.y + v0.z * v0.z + v0.w * v0.w
           + v1.x * v1.x + v1.y * v1.y + v1.z * v1.z + v1.w * v1.w;
#pragma unroll
  for (int s = 32; s > 0; s >>= 1) ss += __shfl_xor(ss, s, 64);
  const float m = fmaxf(sqrtf(ss), EPS_NORM);
  const float rm = 1.0f / m;
  float4 o0, o1;
  o0.x = v0.x * rm; o0.y = v0.y * rm; o0.z = v0.z * rm; o0.w = v0.w * rm;
  o1.x = v1.x * rm; o1.y = v1.y * rm; o1.z = v1.z * rm; o1.w = v1.w * rm;
  float s2 = o0.x * o0.x + o0.y * o0.y + o0.z * o0.z + o0.w * o0.w
           + o1.x * o1.x + o1.y * o1.y + o1.z * o1.z + o1.w * o1.w;
#pragma unroll
  for (int s = 32; s > 0; s >>= 1) s2 += __shfl_xor(s2, s, 64);
  f16x4 h0, h1;
  h0[0] = (_Float16)o0.x; h0[1] = (_Float16)o0.y; h0[2] = (_Float16)o0.z; h0[3] = (_Float16)o0.w;
  h1[0] = (_Float16)o1.x; h1[1] = (_Float16)o1.y; h1[2] = (_Float16)o1.z; h1[3] = (_Float16)o1.w;
  *(f16x4*)(znh + (size_t)row * D_DIM + lane * 4) = h0;
  *(f16x4*)(znh + (size_t)row * D_DIM + 256 + lane * 4) = h1;
  if (lane == 0) { znorm[row] = m; znorm2[row] = s2; }
}

__global__ __launch_bounds__(256) void prep_cb_kernel(
    const float* __restrict__ emb, float* __restrict__ cb32,
    _Float16* __restrict__ cbh, float* __restrict__ cnorm2,
    unsigned* __restrict__ counters) {
  if (blockIdx.x == 0 && threadIdx.x < 2) counters[threadIdx.x] = 0;
  const int row = blockIdx.x * 4 + ((int)threadIdx.x >> 6);
  const int lane = (int)threadIdx.x & 63;
  const float4* xr = (const float4*)(emb + (size_t)row * D_DIM);
  float4 v0 = xr[lane];
  float4 v1 = xr[lane + 64];
  float ss = v0.x * v0.x + v0.y * v0.y + v0.z * v0.z + v0.w * v0.w
           + v1.x * v1.x + v1.y * v1.y + v1.z * v1.z + v1.w * v1.w;
#pragma unroll
  for (int s = 32; s > 0; s >>= 1) ss += __shfl_xor(ss, s, 64);
  const float m = fmaxf(sqrtf(ss), EPS_NORM);
  float4 o0, o1;
  o0.x = v0.x / m; o0.y = v0.y / m; o0.z = v0.z / m; o0.w = v0.w / m;
  o1.x = v1.x / m; o1.y = v1.y / m; o1.z = v1.z / m; o1.w = v1.w / m;
  float s2 = o0.x * o0.x + o0.y * o0.y + o0.z * o0.z + o0.w * o0.w
           + o1.x * o1.x + o1.y * o1.y + o1.z * o1.z + o1.w * o1.w;
#pragma unroll
  for (int s = 32; s > 0; s >>= 1) s2 += __shfl_xor(s2, s, 64);
  float4* co = (float4*)(cb32 + (size_t)row * D_DIM);
  co[lane] = o0;
  co[lane + 64] = o1;
  f16x4 h0, h1;
  h0[0] = (_Float16)o0.x; h0[1] = (_Float16)o0.y; h0[2] = (_Float16)o0.z; h0[3] = (_Float16)o0.w;
  h1[0] = (_Float16)o1.x; h1[1] = (_Float16)o1.y; h1[2] = (_Float16)o1.z; h1[3] = (_Float16)o1.w;
  *(f16x4*)(cbh + (size_t)row * D_DIM + lane * 4) = h0;
  *(f16x4*)(cbh + (size_t)row * D_DIM + 256 + lane * 4) = h1;
  if (lane == 0) cnorm2[row] = s2;
}

// ---------------------------------------------------------------------------
// Screening GEMM v7: EXACT round-3 structure (hardware-validated at 671 us:
// triple-buffered LDS, depth-2 prefetch, vmcnt(4), LGKM0+sched_barrier
// before MFMAs — WAR-safe since the drain precedes the barrier), with ONE
// change: two-level XCD block mapping. xcd=o&7 (round-robin dispatch),
// bx = xcd*8 + (j&7), by = j>>3:
//  - each XCD owns a FIXED 1 MB cbh slice (8 panels)  -> L2-resident
//  - znh by-panel (128 KB) reused by 8 consecutive blocks -> L2-resident,
//    and all XCDs walk by in lockstep -> L3-served 7/8
//  - K1/K2 64B lines written by one XCD within an 8-block window -> merging
// ---------------------------------------------------------------------------
#define LGKM0 asm volatile("s_waitcnt lgkmcnt(0)" ::: "memory")
#define VM4 asm volatile("s_waitcnt vmcnt(4)" ::: "memory")
#define VM0 asm volatile("s_waitcnt vmcnt(0)" ::: "memory")
#define BARF                                                                  \
  do { asm volatile("" ::: "memory"); __builtin_amdgcn_s_barrier();           \
       asm volatile("" ::: "memory"); } while (0)

#define STAGE(b, kt)                                                          \
  do {                                                                        \
    async_copy16(lds + (b) * 8192 + tid * 8,        gZ  + (kt) * 32);         \
    async_copy16(lds + (b) * 8192 + 2048 + tid * 8, gZ2 + (kt) * 32);         \
    async_copy16(lds + (b) * 8192 + 4096 + tid * 8, gC  + (kt) * 32);         \
    async_copy16(lds + (b) * 8192 + 6144 + tid * 8, gC2 + (kt) * 32);         \
  } while (0)

#define COMPUTE(b)                                                            \
  do {                                                                        \
    f16x8 zF[4], cF[4];                                                       \
    _Pragma("unroll") for (int mf_ = 0; mf_ < 4; ++mf_)                       \
      zF[mf_] = *(const f16x8*)(zRd + (b) * 8192 + mf_ * 512);                \
    _Pragma("unroll") for (int nf_ = 0; nf_ < 4; ++nf_)                       \
      cF[nf_] = *(const f16x8*)(cRd + (b) * 8192 + nf_ * 512);                \
    LGKM0;                                                                    \
    __builtin_amdgcn_sched_barrier(0);                                        \
    _Pragma("unroll") for (int nf_ = 0; nf_ < 4; ++nf_)                       \
      _Pragma("unroll") for (int mf_ = 0; mf_ < 4; ++mf_)                     \
        acc[nf_][mf_] = __builtin_amdgcn_mfma_f32_16x16x32_f16(               \
            cF[nf_], zF[mf_], acc[nf_][mf_], 0, 0, 0);                        \
  } while (0)

__global__ __launch_bounds__(256, 3) void screen_gemm_kernel(
    const _Float16* __restrict__ znh, const _Float16* __restrict__ cbh,
    u64* __restrict__ K1, unsigned* __restrict__ K2) {
  __shared__ __align__(16) _Float16 lds[24576];  // 3 x (Z 8KB | C 8KB)
  const int tid = (int)threadIdx.x;
  const int lane = tid & 63;
  const int wv = tid >> 6;       // wave 0..3
  const int wm = wv >> 1;        // 0..1: 64-row (M) strip
  const int wn = wv & 1;         // 0..1: 64-col (N) strip
  const int q = lane >> 4;       // 0..3
  const int c15 = lane & 15;

  // Two-level XCD mapping: fixed bx group per XCD, by advances every 8 blocks.
  const int o = (int)blockIdx.x;
  const int jb = o >> 3;
  const int bx = (o & 7) * 8 + (jb & 7);  // n-block: xcd*8 + local
  const int by = jb >> 3;                 // m-block 0..511
  const int m0 = by * 128;
  const int n0 = bx * 128;

  // Staging sources (chunk-XOR pre-swizzled, linear LDS dest):
  const int srow = tid >> 2;                     // 0..63
  const int sch = (tid & 3) ^ ((tid >> 3) & 3);
  const _Float16* gZ  = znh + (size_t)(m0 + srow) * D_DIM + sch * 8;
  const _Float16* gZ2 = gZ + (size_t)64 * D_DIM;
  const _Float16* gC  = cbh + (size_t)(n0 + srow) * D_DIM + sch * 8;
  const _Float16* gC2 = gC + (size_t)64 * D_DIM;

  // Read side: element k-offset = (q ^ ((row>>1)&3))*8, row parity from c15.
  const int rk = (q ^ ((c15 >> 1) & 3)) * 8;
  const _Float16* zRd = lds + (wm * 64 + c15) * 32 + rk;          // Z region
  const _Float16* cRd = lds + 4096 + (wn * 64 + c15) * 32 + rk;   // C region

  f32x4 acc[4][4];   // acc[nf][mf]: M = wm*64+mf*16+c15, N = wn*64+nf*16+q*4+r
  const f32x4 z4 = {0.0f, 0.0f, 0.0f, 0.0f};
#pragma unroll
  for (int i = 0; i < 4; i++)
#pragma unroll
    for (int jj = 0; jj < 4; jj++) acc[i][jj] = z4;

  // ---- depth-2 pipelined K-loop, 16 tiles, fully static buffers ----
  STAGE(0, 0); STAGE(1, 1);
  VM4; BARF;
  STAGE(2, 2);  COMPUTE(0); VM4; BARF;
  STAGE(0, 3);  COMPUTE(1); VM4; BARF;
  STAGE(1, 4);  COMPUTE(2); VM4; BARF;
  STAGE(2, 5);  COMPUTE(0); VM4; BARF;
  STAGE(0, 6);  COMPUTE(1); VM4; BARF;
  STAGE(1, 7);  COMPUTE(2); VM4; BARF;
  STAGE(2, 8);  COMPUTE(0); VM4; BARF;
  STAGE(0, 9);  COMPUTE(1); VM4; BARF;
  STAGE(1, 10); COMPUTE(2); VM4; BARF;
  STAGE(2, 11); COMPUTE(0); VM4; BARF;
  STAGE(0, 12); COMPUTE(1); VM4; BARF;
  STAGE(1, 13); COMPUTE(2); VM4; BARF;
  STAGE(2, 14); COMPUTE(0); VM4; BARF;
  STAGE(0, 15); COMPUTE(1); VM4; BARF;
  COMPUTE(2); VM0; BARF;
  COMPUTE(0);

  // ---- epilogue: lane-local top1/top2 over 16 N-values, 2 shfl steps ----
  __syncthreads();
  u64* kbuf = (u64*)lds;                       // [128 rows][2 wn] u64 = 2KB
  unsigned* vbuf = (unsigned*)(lds + 1024);    // bytes 2048..3071
#pragma unroll
  for (int mf = 0; mf < 4; ++mf) {
    float v1 = __builtin_inff(), v2 = __builtin_inff();
    int c1 = 0;
#pragma unroll
    for (int nf = 0; nf < 4; ++nf)
#pragma unroll
      for (int r = 0; r < 4; ++r) {
        float v = -acc[nf][mf][r];
        int col = n0 + wn * 64 + nf * 16 + q * 4 + r;
        if (v < v1) { v2 = v1; v1 = v; c1 = col; }
        else        { v2 = fminf(v2, v); }
      }
    u64 key1 = ((u64)orderf(v1) << 32) | (u64)(unsigned)c1;
    unsigned b2 = orderf(v2);
#pragma unroll
    for (int s = 16; s <= 32; s <<= 1) {
      u64 ok = shfl_xor_u64(key1, s);
      unsigned ob2 = (unsigned)__shfl_xor((int)b2, s, 64);
      unsigned ov = (unsigned)(ok >> 32);
      unsigned v1k = (unsigned)(key1 >> 32);
      unsigned lose = (ok < key1) ? v1k : ov;
      b2 = umin32(umin32(b2, ob2), lose);
      key1 = umin64(key1, ok);
    }
    if (q == 0) {
      const int rowL = wm * 64 + mf * 16 + c15;
      kbuf[rowL * 2 + wn] = key1;
      vbuf[rowL * 2 + wn] = b2;
    }
  }
  __syncthreads();
  if (tid < 128) {
    u64 k0 = kbuf[tid * 2], k1v = kbuf[tid * 2 + 1];
    unsigned v0 = vbuf[tid * 2], v1 = vbuf[tid * 2 + 1];
    u64 kk = umin64(k0, k1v);
    unsigned lose = (k0 < k1v) ? (unsigned)(k1v >> 32) : (unsigned)(k0 >> 32);
    unsigned t2 = umin32(umin32(v0, v1), lose);
    const size_t oo = (size_t)(m0 + tid) * NB + bx;
    K1[oo] = kk;
    K2[oo] = t2;
  }
}

// ---------------------------------------------------------------------------
// Certify v2: one wave per row, lane = block.
//  thr = approx_top1 + MARGIN.
//  - any block with top2 <= thr, or >CAP candidates  -> heavy list (rare)
//  - exactly 1 candidate code                        -> certified, done
//  - else                                            -> light list + compact
//                                                       candidate code array
// ---------------------------------------------------------------------------
__global__ __launch_bounds__(256) void certify_kernel(
    const u64* __restrict__ K1, const unsigned* __restrict__ K2,
    unsigned* __restrict__ idx_final, unsigned* __restrict__ candList,
    unsigned* __restrict__ candCount, unsigned* __restrict__ lightList,
    unsigned* __restrict__ heavyList, unsigned* __restrict__ counters) {
  const int row = blockIdx.x * 4 + (int)(threadIdx.x >> 6);
  const int b = (int)(threadIdx.x & 63);
  u64 k = K1[(size_t)row * NB + b];
  unsigned t2 = K2[(size_t)row * NB + b];
  u64 kmin = k;
#pragma unroll
  for (int s = 1; s <= 32; s <<= 1) kmin = umin64(kmin, shfl_xor_u64(kmin, s));
  const float t1f = unorderf((unsigned)(kmin >> 32));
  const unsigned thr = orderf(t1f + MARGIN);
  const bool cand = ((unsigned)(k >> 32)) <= thr;
  const bool heavy = (t2 <= thr);
  u64 cmask = __ballot(cand);
  u64 hmask = __ballot(heavy);
  const int nc = __popcll(cmask);
  if (hmask != 0 || nc > CAP) {
    if (b == 0) {
      unsigned p = atomicAdd(counters + 1, 1u);
      heavyList[p] = (unsigned)row;
    }
  } else if (nc == 1) {
    if (b == 0) idx_final[row] = (unsigned)(kmin & 0xFFFFFFFFull);
  } else {
    if (cand) {
      int pos = __popcll(cmask & ((b == 0) ? 0ull : (~0ull >> (64 - b))));
      candList[(size_t)row * CAP + pos] = (unsigned)(k & 0xFFFFFFFFull);
    }
    if (b == 0) {
      candCount[row] = (unsigned)nc;
      unsigned p = atomicAdd(counters + 0, 1u);
      lightList[p] = (unsigned)row;
    }
  }
}

// ---------------------------------------------------------------------------
// Light rescore: one wave per flagged row; exact fp32 dist for each candidate
// code (coalesced 2KB row reads), argmin with lowest-index tie-break.
// ---------------------------------------------------------------------------
__global__ __launch_bounds__(64) void rescore_light_kernel(
    const float* __restrict__ z, const float* __restrict__ cb32,
    const float* __restrict__ znorm, const float* __restrict__ znorm2,
    const float* __restrict__ cnorm2, const unsigned* __restrict__ candList,
    const unsigned* __restrict__ candCount,
    const unsigned* __restrict__ lightList,
    const unsigned* __restrict__ counters, unsigned* __restrict__ idx_final) {
  const int lane = (int)threadIdx.x;
  const unsigned n = counters[0];
  for (unsigned i = blockIdx.x; i < n; i += gridDim.x) {
    const int row = (int)lightList[i];
    const float m = znorm[row];
    const float zn2 = znorm2[row];
    const float4* zr = (const float4*)(z + (size_t)row * D_DIM);
    float4 v0 = zr[lane], v1 = zr[lane + 64];
    float4 o0, o1;
    o0.x = v0.x / m; o0.y = v0.y / m; o0.z = v0.z / m; o0.w = v0.w / m;
    o1.x = v1.x / m; o1.y = v1.y / m; o1.z = v1.z / m; o1.w = v1.w / m;
    const unsigned nc = candCount[row];
    u64 best = ~0ull;
    for (unsigned j = 0; j < nc; j++) {
      const unsigned c = candList[(size_t)row * CAP + j];
      const float4* qr = (const float4*)(cb32 + (size_t)c * D_DIM);
      float4 q0 = qr[lane], q1 = qr[lane + 64];
      float p = o0.x * q0.x + o0.y * q0.y + o0.z * q0.z + o0.w * q0.w
              + o1.x * q1.x + o1.y * q1.y + o1.z * q1.z + o1.w * q1.w;
#pragma unroll
      for (int s = 32; s > 0; s >>= 1) p += __shfl_xor(p, s, 64);
      float dist = __fadd_rn(__fsub_rn(zn2, __fmul_rn(2.0f, p)), cnorm2[c]);
      u64 key = ((u64)orderf(dist) << 32) | (u64)c;
      best = umin64(best, key);
    }
    if (lane == 0) idx_final[row] = (unsigned)(best & 0xFFFFFFFFull);
  }
}

// ---------------------------------------------------------------------------
// Heavy rescore (rare rows): full fp32 scan of every block whose top-1 is
// within MARGIN (superset of all candidates).
// ---------------------------------------------------------------------------
__global__ __launch_bounds__(64) void rescore_heavy_kernel(
    const float* __restrict__ z, const float* __restrict__ cb32,
    const float* __restrict__ znorm, const float* __restrict__ znorm2,
    const float* __restrict__ cnorm2, const u64* __restrict__ K1,
    const unsigned* __restrict__ heavyList,
    const unsigned* __restrict__ counters, unsigned* __restrict__ idx_final) {
  __shared__ float znl[D_DIM];
  const int lane = (int)threadIdx.x;
  const unsigned n = counters[1];
  for (unsigned i = blockIdx.x; i < n; i += gridDim.x) {
    const int row = (int)heavyList[i];
    const float m = znorm[row];
    const float4* zr = (const float4*)(z + (size_t)row * D_DIM);
    float4 v0 = zr[lane], v1 = zr[lane + 64];
    __syncthreads();
    float4 o0, o1;
    o0.x = v0.x / m; o0.y = v0.y / m; o0.z = v0.z / m; o0.w = v0.w / m;
    o1.x = v1.x / m; o1.y = v1.y / m; o1.z = v1.z / m; o1.w = v1.w / m;
    *(float4*)&znl[lane * 4] = o0;
    *(float4*)&znl[256 + lane * 4] = o1;
    u64 k = K1[(size_t)row * NB + lane];
    u64 kmin = k;
#pragma unroll
    for (int s = 1; s <= 32; s <<= 1) kmin = umin64(kmin, shfl_xor_u64(kmin, s));
    const float t1 = unorderf((unsigned)(kmin >> 32));
    const bool cf = unorderf((unsigned)(k >> 32)) <= t1 + MARGIN;
    u64 mask = __ballot(cf);
    __syncthreads();
    const float zn2 = znorm2[row];
    u64 best = ~0ull;
    while (mask) {
      const int b = __builtin_ctzll(mask);
      mask &= mask - 1;
#pragma unroll
      for (int h = 0; h < 2; h++) {
        const int c = b * 128 + h * 64 + lane;
        const float4* cr = (const float4*)(cb32 + (size_t)c * D_DIM);
        float dot = 0.0f;
        for (int d = 0; d < 128; d++) {
          float4 bb = cr[d];
          float4 aa = *(const float4*)&znl[d * 4];
          dot = __fmaf_rn(aa.x, bb.x, dot);
          dot = __fmaf_rn(aa.y, bb.y, dot);
          dot = __fmaf_rn(aa.z, bb.z, dot);
          dot = __fmaf_rn(aa.w, bb.w, dot);
        }
        float dist = __fadd_rn(__fsub_rn(zn2, __fmul_rn(2.0f, dot)), cnorm2[c]);
        u64 key = ((u64)orderf(dist) << 32) | (u64)(unsigned)c;
        best = umin64(best, key);
      }
    }
#pragma unroll
    for (int s = 1; s <= 32; s <<= 1) best = umin64(best, shfl_xor_u64(best, s));
    if (lane == 0) idx_final[row] = (unsigned)(best & 0xFFFFFFFFull);
  }
}

// ---------------------------------------------------------------------------
// Finalize: gather code, project, write outputs. 4 rows per 256-thread block.
// ---------------------------------------------------------------------------
__global__ __launch_bounds__(256) void finalize_kernel(
    const float* __restrict__ z, const float* __restrict__ cb32,
    const float* __restrict__ znorm, const unsigned* __restrict__ idx_final,
    float* __restrict__ out) {
  const int row = blockIdx.x * 4 + ((int)threadIdx.x >> 6);
  const int lane = (int)threadIdx.x & 63;
  const float m = znorm[row];
  const unsigned idx = idx_final[row];
  const float4* zr = (const float4*)(z + (size_t)row * D_DIM);
  const float4* qr = (const float4*)(cb32 + (size_t)idx * D_DIM);
  float4 v0 = zr[lane], v1 = zr[lane + 64];
  float4 q0 = qr[lane], q1 = qr[lane + 64];
  float4 z0, z1;
  z0.x = v0.x / m; z0.y = v0.y / m; z0.z = v0.z / m; z0.w = v0.w / m;
  z1.x = v1.x / m; z1.y = v1.y / m; z1.z = v1.z / m; z1.w = v1.w / m;
  float p = z0.x * q0.x + z0.y * q0.y + z0.z * q0.z + z0.w * q0.w
          + z1.x * q1.x + z1.y * q1.y + z1.z * q1.z + z1.w * q1.w;
#pragma unroll
  for (int s = 32; s > 0; s >>= 1) p += __shfl_xor(p, s, 64);
  float4 o0, o1;
  o0.x = p * q0.x; o0.y = p * q0.y; o0.z = p * q0.z; o0.w = p * q0.w;
  o1.x = p * q1.x; o1.y = p * q1.y; o1.z = p * q1.z; o1.w = p * q1.w;
  float4* orow = (float4*)(out + (size_t)row * D_DIM);
  orow[lane] = o0;
  orow[lane + 64] = o1;
  if (lane == 0) out[(size_t)N_ROWS * D_DIM + row] = (float)idx;
}

// ---------------------------------------------------------------------------
extern "C" void kernel_launch(void* const* d_in, const int* in_sizes, int n_in,
                              void* d_out, int out_size, void* d_ws,
                              size_t ws_size, hipStream_t stream) {
  const float* z = (const float*)d_in[0];
  const float* emb = (const float*)d_in[1];
  float* out = (float*)d_out;

  // ws layout, ~142 MB total:
  u64* K1 = (u64*)d_ws;                                   // 32 MB
  unsigned* K2 = (unsigned*)(K1 + (size_t)N_ROWS * NB);   // 16 MB
  float* cb32 = (float*)(K2 + (size_t)N_ROWS * NB);       // 16 MB
  float* znorm = cb32 + (size_t)K_CODES * D_DIM;          // 256 KB
  float* znorm2 = znorm + N_ROWS;                         // 256 KB
  float* cnorm2 = znorm2 + N_ROWS;                        // 32 KB
  unsigned* idx_final = (unsigned*)(cnorm2 + K_CODES);    // 256 KB
  unsigned* lightList = idx_final + N_ROWS;               // 256 KB
  unsigned* heavyList = lightList + N_ROWS;               // 256 KB
  unsigned* candCount = heavyList + N_ROWS;               // 256 KB
  unsigned* counters = candCount + N_ROWS;                // 64*4 pad
  unsigned* candList = counters + 64;                     // 4 MB
  _Float16* znh = (_Float16*)(candList + (size_t)N_ROWS * CAP);  // 64 MB
  _Float16* cbh = znh + (size_t)N_ROWS * D_DIM;           // 8 MB

  prep_z_kernel<<<N_ROWS / 4, 256, 0, stream>>>(z, znh, znorm, znorm2);
  prep_cb_kernel<<<K_CODES / 4, 256, 0, stream>>>(emb, cb32, cbh, cnorm2,
                                                  counters);

  screen_gemm_kernel<<<32768, 256, 0, stream>>>(znh, cbh, K1, K2);

  certify_kernel<<<N_ROWS / 4, 256, 0, stream>>>(
      K1, K2, idx_final, candList, candCount, lightList, heavyList, counters);
  rescore_light_kernel<<<8192, 64, 0, stream>>>(
      z, cb32, znorm, znorm2, cnorm2, candList, candCount, lightList, counters,
      idx_final);
  rescore_heavy_kernel<<<512, 64, 0, stream>>>(
      z, cb32, znorm, znorm2, cnorm2, K1, heavyList, counters, idx_final);
  finalize_kernel<<<N_ROWS / 4, 256, 0, stream>>>(z, cb32, znorm, idx_final,
                                                  out);
}

// Round 7
// 1085.372 us; speedup vs baseline: 1.3455x; 1.1413x over previous
//
#include <hip/hip_runtime.h>
#include <stdint.h>

#define N_ROWS 65536
#define K_CODES 8192
#define D_DIM 512
#define EPS_NORM 1e-12f
#define NB 64            // number of 128-wide column blocks
#define MARGIN 2.5e-3f   // > 2x hard bound on fp16 dot error (2*1.01e-3)

typedef _Float16 f16x8 __attribute__((ext_vector_type(8)));
typedef _Float16 f16x4 __attribute__((ext_vector_type(4)));
typedef float f32x4 __attribute__((ext_vector_type(4)));
typedef unsigned long long u64;

__device__ __forceinline__ unsigned orderf(float f) {
  unsigned u = __float_as_uint(f);
  return (u & 0x80000000u) ? ~u : (u | 0x80000000u);
}
__device__ __forceinline__ float unorderf(unsigned ub) {
  unsigned u = (ub & 0x80000000u) ? (ub & 0x7FFFFFFFu) : ~ub;
  return __uint_as_float(u);
}
__device__ __forceinline__ unsigned umin32(unsigned a, unsigned b) { return a < b ? a : b; }
__device__ __forceinline__ u64 umin64(u64 a, u64 b) { return a < b ? a : b; }
__device__ __forceinline__ u64 shfl_xor_u64(u64 v, int m) {
  unsigned lo = (unsigned)__shfl_xor((int)(unsigned)(v & 0xFFFFFFFFull), m, 64);
  unsigned hi = (unsigned)__shfl_xor((int)(unsigned)(v >> 32), m, 64);
  return ((u64)hi << 32) | (u64)lo;
}
__device__ __forceinline__ void async_copy16(void* lds, const void* g) {
  __builtin_amdgcn_global_load_lds(
      (const __attribute__((address_space(1))) void*)g,
      (__attribute__((address_space(3))) void*)lds, 16, 0, 0);
}

// ---------------------------------------------------------------------------
// prep: L2-normalize rows (F.normalize semantics), emit fp16 copy for MFMA.
// 4 rows per 256-thread block. prep_z uses rm-multiply (argmin-safe: all
// exact-path consumers re-divide raw z; znorm2 shift is row-constant).
// ---------------------------------------------------------------------------
__global__ __launch_bounds__(256) void prep_z_kernel(
    const float* __restrict__ z, _Float16* __restrict__ znh,
    float* __restrict__ znorm, float* __restrict__ znorm2) {
  const int row = blockIdx.x * 4 + ((int)threadIdx.x >> 6);
  const int lane = (int)threadIdx.x & 63;
  const float4* xr = (const float4*)(z + (size_t)row * D_DIM);
  float4 v0 = xr[lane];
  float4 v1 = xr[lane + 64];
  float ss = v0.x * v0.x + v0.y * v0.y + v0.z * v0.z + v0.w * v0.w
           + v1.x * v1.x + v1.y * v1.y + v1.z * v1.z + v1.w * v1.w;
#pragma unroll
  for (int s = 32; s > 0; s >>= 1) ss += __shfl_xor(ss, s, 64);
  const float m = fmaxf(sqrtf(ss), EPS_NORM);
  const float rm = 1.0f / m;
  float4 o0, o1;
  o0.x = v0.x * rm; o0.y = v0.y * rm; o0.z = v0.z * rm; o0.w = v0.w * rm;
  o1.x = v1.x * rm; o1.y = v1.y * rm; o1.z = v1.z * rm; o1.w = v1.w * rm;
  float s2 = o0.x * o0.x + o0.y * o0.y + o0.z * o0.z + o0.w * o0.w
           + o1.x * o1.x + o1.y * o1.y + o1.z * o1.z + o1.w * o1.w;
#pragma unroll
  for (int s = 32; s > 0; s >>= 1) s2 += __shfl_xor(s2, s, 64);
  f16x4 h0, h1;
  h0[0] = (_Float16)o0.x; h0[1] = (_Float16)o0.y; h0[2] = (_Float16)o0.z; h0[3] = (_Float16)o0.w;
  h1[0] = (_Float16)o1.x; h1[1] = (_Float16)o1.y; h1[2] = (_Float16)o1.z; h1[3] = (_Float16)o1.w;
  *(f16x4*)(znh + (size_t)row * D_DIM + lane * 4) = h0;
  *(f16x4*)(znh + (size_t)row * D_DIM + 256 + lane * 4) = h1;
  if (lane == 0) { znorm[row] = m; znorm2[row] = s2; }
}

__global__ __launch_bounds__(256) void prep_cb_kernel(
    const float* __restrict__ emb, float* __restrict__ cb32,
    _Float16* __restrict__ cbh, float* __restrict__ cnorm2) {
  const int row = blockIdx.x * 4 + ((int)threadIdx.x >> 6);
  const int lane = (int)threadIdx.x & 63;
  const float4* xr = (const float4*)(emb + (size_t)row * D_DIM);
  float4 v0 = xr[lane];
  float4 v1 = xr[lane + 64];
  float ss = v0.x * v0.x + v0.y * v0.y + v0.z * v0.z + v0.w * v0.w
           + v1.x * v1.x + v1.y * v1.y + v1.z * v1.z + v1.w * v1.w;
#pragma unroll
  for (int s = 32; s > 0; s >>= 1) ss += __shfl_xor(ss, s, 64);
  const float m = fmaxf(sqrtf(ss), EPS_NORM);
  float4 o0, o1;
  o0.x = v0.x / m; o0.y = v0.y / m; o0.z = v0.z / m; o0.w = v0.w / m;
  o1.x = v1.x / m; o1.y = v1.y / m; o1.z = v1.z / m; o1.w = v1.w / m;
  float s2 = o0.x * o0.x + o0.y * o0.y + o0.z * o0.z + o0.w * o0.w
           + o1.x * o1.x + o1.y * o1.y + o1.z * o1.z + o1.w * o1.w;
#pragma unroll
  for (int s = 32; s > 0; s >>= 1) s2 += __shfl_xor(s2, s, 64);
  float4* co = (float4*)(cb32 + (size_t)row * D_DIM);
  co[lane] = o0;
  co[lane + 64] = o1;
  f16x4 h0, h1;
  h0[0] = (_Float16)o0.x; h0[1] = (_Float16)o0.y; h0[2] = (_Float16)o0.z; h0[3] = (_Float16)o0.w;
  h1[0] = (_Float16)o1.x; h1[1] = (_Float16)o1.y; h1[2] = (_Float16)o1.z; h1[3] = (_Float16)o1.w;
  *(f16x4*)(cbh + (size_t)row * D_DIM + lane * 4) = h0;
  *(f16x4*)(cbh + (size_t)row * D_DIM + 256 + lane * 4) = h1;
  if (lane == 0) cnorm2[row] = s2;
}

// ---------------------------------------------------------------------------
// Screening GEMM v7 (UNCHANGED from round 6 — hardware-validated, 659 us,
// 835 TF ~= 95% of the 128^2/2-sync structure ceiling): triple-buffered LDS,
// depth-2 prefetch, counted vmcnt(4), two-level XCD mapping (fixed 1 MB cbh
// slice per XCD -> FETCH 266 MB), chunk-XOR conflict-free LDS.
// ---------------------------------------------------------------------------
#define LGKM0 asm volatile("s_waitcnt lgkmcnt(0)" ::: "memory")
#define VM4 asm volatile("s_waitcnt vmcnt(4)" ::: "memory")
#define VM0 asm volatile("s_waitcnt vmcnt(0)" ::: "memory")
#define BARF                                                                  \
  do { asm volatile("" ::: "memory"); __builtin_amdgcn_s_barrier();           \
       asm volatile("" ::: "memory"); } while (0)

#define STAGE(b, kt)                                                          \
  do {                                                                        \
    async_copy16(lds + (b) * 8192 + tid * 8,        gZ  + (kt) * 32);         \
    async_copy16(lds + (b) * 8192 + 2048 + tid * 8, gZ2 + (kt) * 32);         \
    async_copy16(lds + (b) * 8192 + 4096 + tid * 8, gC  + (kt) * 32);         \
    async_copy16(lds + (b) * 8192 + 6144 + tid * 8, gC2 + (kt) * 32);         \
  } while (0)

#define COMPUTE(b)                                                            \
  do {                                                                        \
    f16x8 zF[4], cF[4];                                                       \
    _Pragma("unroll") for (int mf_ = 0; mf_ < 4; ++mf_)                       \
      zF[mf_] = *(const f16x8*)(zRd + (b) * 8192 + mf_ * 512);                \
    _Pragma("unroll") for (int nf_ = 0; nf_ < 4; ++nf_)                       \
      cF[nf_] = *(const f16x8*)(cRd + (b) * 8192 + nf_ * 512);                \
    LGKM0;                                                                    \
    __builtin_amdgcn_sched_barrier(0);                                        \
    _Pragma("unroll") for (int nf_ = 0; nf_ < 4; ++nf_)                       \
      _Pragma("unroll") for (int mf_ = 0; mf_ < 4; ++mf_)                     \
        acc[nf_][mf_] = __builtin_amdgcn_mfma_f32_16x16x32_f16(               \
            cF[nf_], zF[mf_], acc[nf_][mf_], 0, 0, 0);                        \
  } while (0)

__global__ __launch_bounds__(256, 3) void screen_gemm_kernel(
    const _Float16* __restrict__ znh, const _Float16* __restrict__ cbh,
    u64* __restrict__ K1, unsigned* __restrict__ K2) {
  __shared__ __align__(16) _Float16 lds[24576];  // 3 x (Z 8KB | C 8KB)
  const int tid = (int)threadIdx.x;
  const int lane = tid & 63;
  const int wv = tid >> 6;       // wave 0..3
  const int wm = wv >> 1;        // 0..1: 64-row (M) strip
  const int wn = wv & 1;         // 0..1: 64-col (N) strip
  const int q = lane >> 4;       // 0..3
  const int c15 = lane & 15;

  // Two-level XCD mapping: fixed bx group per XCD, by advances every 8 blocks.
  const int o = (int)blockIdx.x;
  const int jb = o >> 3;
  const int bx = (o & 7) * 8 + (jb & 7);  // n-block: xcd*8 + local
  const int by = jb >> 3;                 // m-block 0..511
  const int m0 = by * 128;
  const int n0 = bx * 128;

  // Staging sources (chunk-XOR pre-swizzled, linear LDS dest):
  const int srow = tid >> 2;                     // 0..63
  const int sch = (tid & 3) ^ ((tid >> 3) & 3);
  const _Float16* gZ  = znh + (size_t)(m0 + srow) * D_DIM + sch * 8;
  const _Float16* gZ2 = gZ + (size_t)64 * D_DIM;
  const _Float16* gC  = cbh + (size_t)(n0 + srow) * D_DIM + sch * 8;
  const _Float16* gC2 = gC + (size_t)64 * D_DIM;

  // Read side: element k-offset = (q ^ ((row>>1)&3))*8, row parity from c15.
  const int rk = (q ^ ((c15 >> 1) & 3)) * 8;
  const _Float16* zRd = lds + (wm * 64 + c15) * 32 + rk;          // Z region
  const _Float16* cRd = lds + 4096 + (wn * 64 + c15) * 32 + rk;   // C region

  f32x4 acc[4][4];   // acc[nf][mf]: M = wm*64+mf*16+c15, N = wn*64+nf*16+q*4+r
  const f32x4 z4 = {0.0f, 0.0f, 0.0f, 0.0f};
#pragma unroll
  for (int i = 0; i < 4; i++)
#pragma unroll
    for (int jj = 0; jj < 4; jj++) acc[i][jj] = z4;

  // ---- depth-2 pipelined K-loop, 16 tiles, fully static buffers ----
  STAGE(0, 0); STAGE(1, 1);
  VM4; BARF;
  STAGE(2, 2);  COMPUTE(0); VM4; BARF;
  STAGE(0, 3);  COMPUTE(1); VM4; BARF;
  STAGE(1, 4);  COMPUTE(2); VM4; BARF;
  STAGE(2, 5);  COMPUTE(0); VM4; BARF;
  STAGE(0, 6);  COMPUTE(1); VM4; BARF;
  STAGE(1, 7);  COMPUTE(2); VM4; BARF;
  STAGE(2, 8);  COMPUTE(0); VM4; BARF;
  STAGE(0, 9);  COMPUTE(1); VM4; BARF;
  STAGE(1, 10); COMPUTE(2); VM4; BARF;
  STAGE(2, 11); COMPUTE(0); VM4; BARF;
  STAGE(0, 12); COMPUTE(1); VM4; BARF;
  STAGE(1, 13); COMPUTE(2); VM4; BARF;
  STAGE(2, 14); COMPUTE(0); VM4; BARF;
  STAGE(0, 15); COMPUTE(1); VM4; BARF;
  COMPUTE(2); VM0; BARF;
  COMPUTE(0);

  // ---- epilogue: lane-local top1/top2 over 16 N-values, 2 shfl steps ----
  __syncthreads();
  u64* kbuf = (u64*)lds;                       // [128 rows][2 wn] u64 = 2KB
  unsigned* vbuf = (unsigned*)(lds + 1024);    // bytes 2048..3071
#pragma unroll
  for (int mf = 0; mf < 4; ++mf) {
    float v1 = __builtin_inff(), v2 = __builtin_inff();
    int c1 = 0;
#pragma unroll
    for (int nf = 0; nf < 4; ++nf)
#pragma unroll
      for (int r = 0; r < 4; ++r) {
        float v = -acc[nf][mf][r];
        int col = n0 + wn * 64 + nf * 16 + q * 4 + r;
        if (v < v1) { v2 = v1; v1 = v; c1 = col; }
        else        { v2 = fminf(v2, v); }
      }
    u64 key1 = ((u64)orderf(v1) << 32) | (u64)(unsigned)c1;
    unsigned b2 = orderf(v2);
#pragma unroll
    for (int s = 16; s <= 32; s <<= 1) {
      u64 ok = shfl_xor_u64(key1, s);
      unsigned ob2 = (unsigned)__shfl_xor((int)b2, s, 64);
      unsigned ov = (unsigned)(ok >> 32);
      unsigned v1k = (unsigned)(key1 >> 32);
      unsigned lose = (ok < key1) ? v1k : ov;
      b2 = umin32(umin32(b2, ob2), lose);
      key1 = umin64(key1, ok);
    }
    if (q == 0) {
      const int rowL = wm * 64 + mf * 16 + c15;
      kbuf[rowL * 2 + wn] = key1;
      vbuf[rowL * 2 + wn] = b2;
    }
  }
  __syncthreads();
  if (tid < 128) {
    u64 k0 = kbuf[tid * 2], k1v = kbuf[tid * 2 + 1];
    unsigned v0 = vbuf[tid * 2], v1 = vbuf[tid * 2 + 1];
    u64 kk = umin64(k0, k1v);
    unsigned lose = (k0 < k1v) ? (unsigned)(k1v >> 32) : (unsigned)(k0 >> 32);
    unsigned t2 = umin32(umin32(v0, v1), lose);
    const size_t oo = (size_t)(m0 + tid) * NB + bx;
    K1[oo] = kk;
    K2[oo] = t2;
  }
}

// ---------------------------------------------------------------------------
// Resolve: fused certify + light rescore + heavy rescore + finalize.
// One wave per row (4 rows per 256-thread block). Per row:
//  1. certify from K1/K2 (same thresholds/semantics as before)
//  2. nc==1 & no heavy flag  -> idx = top1 code
//     hmask==0               -> light: exact-rescore every candidate block's
//                               top-1 code (unbounded count — CAP removed;
//                               valid because exact-best must be a block
//                               top-1 when no block top-2 is within margin)
//     else                   -> heavy: full scan of flagged blocks using a
//                               per-wave LDS slice (no block-level sync)
//  3. projection + output write (old finalize, same arithmetic)
// ---------------------------------------------------------------------------
__global__ __launch_bounds__(256) void resolve_kernel(
    const float* __restrict__ z, const float* __restrict__ cb32,
    const float* __restrict__ znorm, const float* __restrict__ znorm2,
    const float* __restrict__ cnorm2, const u64* __restrict__ K1,
    const unsigned* __restrict__ K2, float* __restrict__ out) {
  __shared__ float znl[4][D_DIM];              // per-wave slice (heavy only)
  const int w = (int)threadIdx.x >> 6;
  const int lane = (int)threadIdx.x & 63;
  const int row = (int)blockIdx.x * 4 + w;

  // ---- certify ----
  u64 k = K1[(size_t)row * NB + lane];
  unsigned t2 = K2[(size_t)row * NB + lane];
  u64 kmin = k;
#pragma unroll
  for (int s = 1; s <= 32; s <<= 1) kmin = umin64(kmin, shfl_xor_u64(kmin, s));
  const float t1f = unorderf((unsigned)(kmin >> 32));
  const unsigned thr = orderf(t1f + MARGIN);
  const bool cand = ((unsigned)(k >> 32)) <= thr;
  const bool heavy = (t2 <= thr);
  u64 cmask = __ballot(cand);
  u64 hmask = __ballot(heavy);

  // ---- load + normalize z row (needed by every path) ----
  const float m = znorm[row];
  const float4* zr = (const float4*)(z + (size_t)row * D_DIM);
  float4 v0 = zr[lane], v1 = zr[lane + 64];
  float4 o0, o1;
  o0.x = v0.x / m; o0.y = v0.y / m; o0.z = v0.z / m; o0.w = v0.w / m;
  o1.x = v1.x / m; o1.y = v1.y / m; o1.z = v1.z / m; o1.w = v1.w / m;

  unsigned idx;
  if (hmask == 0 && __popcll(cmask) == 1) {
    idx = (unsigned)(kmin & 0xFFFFFFFFull);
  } else if (hmask == 0) {
    // light: candidates are the top-1 codes of flagged blocks
    const float zn2 = znorm2[row];
    u64 best = ~0ull;
    u64 mm = cmask;
    while (mm) {
      const int b = __builtin_ctzll(mm);
      mm &= mm - 1;
      const unsigned c =
          (unsigned)__shfl((int)(unsigned)(k & 0xFFFFFFFFull), b, 64);
      const float4* qr = (const float4*)(cb32 + (size_t)c * D_DIM);
      float4 q0 = qr[lane], q1 = qr[lane + 64];
      float p = o0.x * q0.x + o0.y * q0.y + o0.z * q0.z + o0.w * q0.w
              + o1.x * q1.x + o1.y * q1.y + o1.z * q1.z + o1.w * q1.w;
#pragma unroll
      for (int s = 32; s > 0; s >>= 1) p += __shfl_xor(p, s, 64);
      float dist = __fadd_rn(__fsub_rn(zn2, __fmul_rn(2.0f, p)), cnorm2[c]);
      u64 key = ((u64)orderf(dist) << 32) | (u64)c;
      best = umin64(best, key);
    }
    idx = (unsigned)(best & 0xFFFFFFFFull);
  } else {
    // heavy: full scan of every flagged block, per-wave LDS slice
    *(float4*)&znl[w][lane * 4] = o0;
    *(float4*)&znl[w][256 + lane * 4] = o1;
    const float zn2 = znorm2[row];
    u64 best = ~0ull;
    u64 mm = cmask;
    while (mm) {
      const int b = __builtin_ctzll(mm);
      mm &= mm - 1;
#pragma unroll
      for (int h = 0; h < 2; h++) {
        const int c = b * 128 + h * 64 + lane;
        const float4* cr = (const float4*)(cb32 + (size_t)c * D_DIM);
        float dot = 0.0f;
        for (int d = 0; d < 128; d++) {
          float4 bb = cr[d];
          float4 aa = *(const float4*)&znl[w][d * 4];
          dot = __fmaf_rn(aa.x, bb.x, dot);
          dot = __fmaf_rn(aa.y, bb.y, dot);
          dot = __fmaf_rn(aa.z, bb.z, dot);
          dot = __fmaf_rn(aa.w, bb.w, dot);
        }
        float dist = __fadd_rn(__fsub_rn(zn2, __fmul_rn(2.0f, dot)), cnorm2[c]);
        u64 key = ((u64)orderf(dist) << 32) | (u64)(unsigned)c;
        best = umin64(best, key);
      }
    }
#pragma unroll
    for (int s = 1; s <= 32; s <<= 1) best = umin64(best, shfl_xor_u64(best, s));
    idx = (unsigned)(best & 0xFFFFFFFFull);
  }

  // ---- finalize: projection + output (same arithmetic as before) ----
  const float4* qr = (const float4*)(cb32 + (size_t)idx * D_DIM);
  float4 q0 = qr[lane], q1 = qr[lane + 64];
  float p = o0.x * q0.x + o0.y * q0.y + o0.z * q0.z + o0.w * q0.w
          + o1.x * q1.x + o1.y * q1.y + o1.z * q1.z + o1.w * q1.w;
#pragma unroll
  for (int s = 32; s > 0; s >>= 1) p += __shfl_xor(p, s, 64);
  float4 r0, r1;
  r0.x = p * q0.x; r0.y = p * q0.y; r0.z = p * q0.z; r0.w = p * q0.w;
  r1.x = p * q1.x; r1.y = p * q1.y; r1.z = p * q1.z; r1.w = p * q1.w;
  float4* orow = (float4*)(out + (size_t)row * D_DIM);
  orow[lane] = r0;
  orow[lane + 64] = r1;
  if (lane == 0) out[(size_t)N_ROWS * D_DIM + row] = (float)idx;
}

// ---------------------------------------------------------------------------
extern "C" void kernel_launch(void* const* d_in, const int* in_sizes, int n_in,
                              void* d_out, int out_size, void* d_ws,
                              size_t ws_size, hipStream_t stream) {
  const float* z = (const float*)d_in[0];
  const float* emb = (const float*)d_in[1];
  float* out = (float*)d_out;

  // ws layout, ~136.5 MB total (under the previously-validated ~142 MB):
  u64* K1 = (u64*)d_ws;                                   // 32 MB
  unsigned* K2 = (unsigned*)(K1 + (size_t)N_ROWS * NB);   // 16 MB
  float* cb32 = (float*)(K2 + (size_t)N_ROWS * NB);       // 16 MB
  float* znorm = cb32 + (size_t)K_CODES * D_DIM;          // 256 KB
  float* znorm2 = znorm + N_ROWS;                         // 256 KB
  float* cnorm2 = znorm2 + N_ROWS;                        // 32 KB
  _Float16* znh = (_Float16*)(cnorm2 + K_CODES);          // 64 MB
  _Float16* cbh = znh + (size_t)N_ROWS * D_DIM;           // 8 MB

  prep_z_kernel<<<N_ROWS / 4, 256, 0, stream>>>(z, znh, znorm, znorm2);
  prep_cb_kernel<<<K_CODES / 4, 256, 0, stream>>>(emb, cb32, cbh, cnorm2);

  screen_gemm_kernel<<<32768, 256, 0, stream>>>(znh, cbh, K1, K2);

  resolve_kernel<<<N_ROWS / 4, 256, 0, stream>>>(
      z, cb32, znorm, znorm2, cnorm2, K1, K2, out);
}